// Round 4
// baseline (955.754 us; speedup 1.0000x reference)
//
#include <hip/hip_runtime.h>
#include <hip/hip_bf16.h>
#include <math.h>

#define H 512
#define NL 4
#define N2 32
#define Bsz 8
#define Lseq 4096
#define BT (Bsz*Lseq)        // 32768 total positions
#define LC2 64               // chunk length
#define NCC (BT/LC2)         // 512 chunks total
#define CPB (Lseq/LC2)       // 64 chunks per batch element

typedef __attribute__((ext_vector_type(8))) short short8;   // 8 bf16
typedef __attribute__((ext_vector_type(4))) float float4v;

// ---------------- ws layout (bytes) ----------------
// 0         : xR   (bf16 BT*H residual)        33554432
// 67108864  : Sloc (bf16 H*NCC*64)             33554432
// 100663296 : u_t  (bf16 H*BT) / ybf overlay   33554432
// 134217728 : y_t  (bf16 H*BT) / yo overlay    33554432
// 167772160 : Wbf  (bf16 NL*2H*H)               4194304
// 171966464 : WV   (bf16 H*64*64, Wstate->V)    4194304
// 176160768 : kmat (bf16 NL*H*64)                262144
// 176422912 : dA   (fp32 NL*N2*2*H)              524288
// 176947200 : Ct   (fp32 NL*N2*2*H)              524288

__device__ __forceinline__ float bf2f(unsigned short u) {
    union { unsigned int i; float f; } x; x.i = ((unsigned int)u) << 16; return x.f;
}
__device__ __forceinline__ unsigned short f2bf(float f) {
    union { float f; unsigned int i; } x; x.f = f;
    unsigned int u = x.i + 0x7fff + ((x.i >> 16) & 1);
    return (unsigned short)(u >> 16);
}
__device__ __forceinline__ uint2 pack4bf(float a, float b, float c, float d) {
    uint2 r;
    r.x = (unsigned)f2bf(a) | ((unsigned)f2bf(b) << 16);
    r.y = (unsigned)f2bf(c) | ((unsigned)f2bf(d) << 16);
    return r;
}
__device__ __forceinline__ void async_copy16(const void* g, void* l) {
    __builtin_amdgcn_global_load_lds(
        (const __attribute__((address_space(1))) void*)g,
        (__attribute__((address_space(3))) void*)l, 16, 0, 0);
}
// position-pinned 16B global->reg load (manual vmcnt accounting; no compiler waitcnt!)
__device__ __forceinline__ void gload16(short8* d, const unsigned short* p) {
    asm volatile("global_load_dwordx4 %0, %1, off" : "=v"(*d) : "v"(p) : "memory");
}

// ---------- convert W to bf16 ----------
__global__ void wconv_kernel(const float* __restrict__ W, unsigned short* __restrict__ Wbf) {
    int tid = blockIdx.x * 256 + threadIdx.x;
    Wbf[tid] = f2bf(W[tid]);
}

// ---------- per-(layer,n,h): dA = log(lambda), Ct = 2C(lambda-1)/A ----------
__global__ void params_kernel(const float* __restrict__ log_dt, const float* __restrict__ A_imag,
                              const float* __restrict__ log_A_real, const float* __restrict__ Cin,
                              float* __restrict__ dA, float* __restrict__ Ct) {
    int tid = blockIdx.x * 256 + threadIdx.x;   // ((layer*N2+n)*H + h)
    int h = tid % H;
    int n = (tid / H) % N2;
    int layer = tid / (H * N2);
    float dt = expf(log_dt[layer * H + h]);
    int pidx = (layer * H + h) * N2 + n;
    float Are = -expf(log_A_real[pidx]);
    float Aim = A_imag[pidx];
    float dre = Are * dt, dim = Aim * dt;
    float er = expf(dre);
    float lre = er * cosf(dim), lim = er * sinf(dim);
    float nre = lre - 1.0f, nim = lim;
    float inv = 1.0f / (Are * Are + Aim * Aim);
    float tre = (nre * Are + nim * Aim) * inv;
    float tim = (nim * Are - nre * Aim) * inv;
    float Ccre = Cin[pidx * 2], Ccim = Cin[pidx * 2 + 1];
    int oidx = ((layer * N2 + n) * 2) * H + h;
    dA[oidx] = dre;  dA[oidx + H] = dim;
    Ct[oidx] = 2.0f * (Ccre * tre - Ccim * tim);
    Ct[oidx + H] = 2.0f * (Ccre * tim + Ccim * tre);
}

// ---------- kernels k[d] = Re sum_n Ct_n lambda_n^d, all layers ----------
__global__ void kergen_k_kernel(const float* __restrict__ dA, const float* __restrict__ Ct,
                                unsigned short* __restrict__ kmat) {
    int t = blockIdx.x * 256 + threadIdx.x;     // (layer*H + h)*64 + d
    int d = t & 63;
    int h = (t >> 6) & (H - 1);
    int layer = t >> 15;
    float fd = (float)d;
    float sum = 0.f;
    for (int n = 0; n < N2; n++) {
        int base = ((layer * N2 + n) * 2) * H + h;
        float dre = dA[base], dim = dA[base + H];
        float Ctr = Ct[base], Cti = Ct[base + H];
        float e = expf(dre * fd);
        sum += Ctr * e * cosf(dim * fd) - Cti * e * sinf(dim * fd);
    }
    kmat[t] = f2bf(sum);
}

// ---------- Wstate[h][r][j]: r=2n -> Re(l^(63-j)), r=2n+1 -> Im ----------
__global__ void kergenW_kernel(const float* __restrict__ dA, unsigned short* __restrict__ Wst, int layer) {
    int t = blockIdx.x * 256 + threadIdx.x;     // (h*64 + r)*64 + j
    int j = t & 63;
    int r = (t >> 6) & 63;
    int h = t >> 12;
    int n = r >> 1;
    int base = ((layer * N2 + n) * 2) * H + h;
    float dre = dA[base], dim = dA[base + H];
    float p = (float)(63 - j);
    float e = expf(dre * p);
    Wst[t] = f2bf((r & 1) ? e * sinf(dim * p) : e * cosf(dim * p));
}

// ---------- V[h][l][c2]: c2=2n -> Re(Ct l^(l+1)), c2=2n+1 -> -Im ----------
__global__ void kergenV_kernel(const float* __restrict__ dA, const float* __restrict__ Ct,
                               unsigned short* __restrict__ Vl, int layer) {
    int t = blockIdx.x * 256 + threadIdx.x;     // (h*64 + l)*64 + c2
    int c2 = t & 63;
    int l = (t >> 6) & 63;
    int h = t >> 12;
    int n = c2 >> 1;
    int base = ((layer * N2 + n) * 2) * H + h;
    float dre = dA[base], dim = dA[base + H];
    float Ctr = Ct[base], Cti = Ct[base + H];
    float q = (float)(l + 1);
    float e = expf(dre * q);
    float ar = e * cosf(dim * q), ai = e * sinf(dim * q);
    float vre = Ctr * ar - Cti * ai;
    float vim = Ctr * ai + Cti * ar;
    Vl[t] = f2bf((c2 & 1) ? -vim : vre);
}

// ---------- transpose x fp32 (BT,H) -> u_t bf16 (H,BT)  [layer 0] ----------
__global__ __launch_bounds__(256) void t1_f32_kernel(const float* __restrict__ xi,
                                                     unsigned short* __restrict__ ut) {
    __shared__ float tile[64][68];
    int bx = blockIdx.x;
    int pt = bx & 511, ht = bx >> 9;
    int p0 = pt * 64, h0 = ht * 64;
    int t = threadIdx.x;
    int jr = t & 15, ib = t >> 4;
#pragma unroll
    for (int pass = 0; pass < 4; pass++) {
        int i = ib + pass * 16;
        float4 v = *(const float4*)(xi + (size_t)(p0 + i) * H + h0 + jr * 4);
        tile[i][jr * 4 + 0] = v.x; tile[i][jr * 4 + 1] = v.y;
        tile[i][jr * 4 + 2] = v.z; tile[i][jr * 4 + 3] = v.w;
    }
    __syncthreads();
#pragma unroll
    for (int pass = 0; pass < 4; pass++) {
        int i2 = ib + pass * 16;
        int j2 = jr * 4;
        uint2 pk = pack4bf(tile[j2][i2], tile[j2 + 1][i2], tile[j2 + 2][i2], tile[j2 + 3][i2]);
        *(uint2*)(ut + (size_t)(h0 + i2) * BT + p0 + j2) = pk;
    }
}

// ---------- transpose xR bf16 (BT,H) -> u_t bf16 (H,BT)  [layers >=1] ----------
__global__ __launch_bounds__(256) void t1_bf16_kernel(const unsigned short* __restrict__ xi,
                                                      unsigned short* __restrict__ ut) {
    __shared__ unsigned short tile[64][72];
    int bx = blockIdx.x;
    int pt = bx & 511, ht = bx >> 9;
    int p0 = pt * 64, h0 = ht * 64;
    int t = threadIdx.x;
    int jr = t & 7, ib = t >> 3;
#pragma unroll
    for (int pass = 0; pass < 2; pass++) {
        int i = ib + pass * 32;   // bt-row within tile
        short8 v = *reinterpret_cast<const short8*>(xi + (size_t)(p0 + i) * H + h0 + jr * 8);
#pragma unroll
        for (int e = 0; e < 8; e++) tile[i][jr * 8 + e] = (unsigned short)v[e];
    }
    __syncthreads();
    int hr = t >> 2, bg = t & 3;
    short8 o0, o1;
#pragma unroll
    for (int r = 0; r < 8; r++) o0[r] = (short)tile[bg * 16 + r][hr];
#pragma unroll
    for (int r = 0; r < 8; r++) o1[r] = (short)tile[bg * 16 + 8 + r][hr];
    unsigned short* dst = ut + (size_t)(h0 + hr) * BT + p0 + bg * 16;
    *reinterpret_cast<short8*>(dst) = o0;
    *reinterpret_cast<short8*>(dst + 8) = o1;
}

// ---------- local chunk states: Sloc[h][cc][r] = sum_j Wst[r][j] u[cc*64+j] ----------
__global__ __launch_bounds__(256) void states_kernel(const unsigned short* __restrict__ ut,
                                                     const unsigned short* __restrict__ Wst,
                                                     unsigned short* __restrict__ Sloc) {
    int h = blockIdx.x;
    int wave = threadIdx.x >> 6, lane = threadIdx.x & 63;
    int r16 = lane & 15, quad = lane >> 4;
    const unsigned short* uh = ut + (size_t)h * BT;
    const unsigned short* wh = Wst + (size_t)h * 64 * 64;
    unsigned short* sh = Sloc + (size_t)h * NCC * 64;
    for (int nt = 0; nt < 8; nt++) {
        int cc0 = wave * 128 + nt * 16;
        float4v acc[4] = {};
#pragma unroll
        for (int k0 = 0; k0 < 64; k0 += 32) {
            short8 bf = *reinterpret_cast<const short8*>(uh + (size_t)(cc0 + r16) * 64 + k0 + quad * 8);
#pragma unroll
            for (int mt = 0; mt < 4; mt++) {
                short8 af = *reinterpret_cast<const short8*>(wh + (mt * 16 + r16) * 64 + k0 + quad * 8);
                acc[mt] = __builtin_amdgcn_mfma_f32_16x16x32_bf16(af, bf, acc[mt], 0, 0, 0);
            }
        }
        int cc = cc0 + r16;
#pragma unroll
        for (int mt = 0; mt < 4; mt++) {
            uint2 pk = pack4bf(acc[mt][0], acc[mt][1], acc[mt][2], acc[mt][3]);
            *(uint2*)(sh + (size_t)cc * 64 + mt * 16 + quad * 4) = pk;
        }
    }
}

// ---------- combine: in-place scan over chunks; Sloc becomes ENTERING state ----------
__global__ void combine_kernel(unsigned short* __restrict__ Sloc, const float* __restrict__ dA, int layer) {
    int t = blockIdx.x * 256 + threadIdx.x;     // n(32) | b(8) | h(512)
    int n = t & 31;
    int b = (t >> 5) & 7;
    int h = t >> 8;
    int base = ((layer * N2 + n) * 2) * H + h;
    float dre = dA[base], dim = dA[base + H];
    float e = expf(dre * 64.f);
    float Lr = e * cosf(dim * 64.f), Li = e * sinf(dim * 64.f);
    unsigned int* p = (unsigned int*)Sloc + ((size_t)h * NCC + b * CPB) * 32 + n;
    float sr = 0.f, si = 0.f;
    for (int c = 0; c < CPB; c++) {
        unsigned int v = p[(size_t)c * 32];
        float pr = bf2f(v & 0xffff), pi = bf2f(v >> 16);
        p[(size_t)c * 32] = (unsigned)f2bf(sr) | ((unsigned)f2bf(si) << 16);
        float nr = fmaf(Lr, sr, fmaf(-Li, si, pr));
        float ni = fmaf(Lr, si, fmaf(Li, sr, pi));
        sr = nr; si = ni;
    }
}

// ---------- conv: Toeplitz GEMM + state-correction GEMM + D*u + gelu -> y_t ----------
__global__ __launch_bounds__(256) void conv_kernel(const unsigned short* __restrict__ ut,
                                                   const unsigned short* __restrict__ kmat,
                                                   const unsigned short* __restrict__ Vl,
                                                   const unsigned short* __restrict__ Sent,
                                                   const float* __restrict__ Dp,
                                                   unsigned short* __restrict__ yt, int layer) {
    __shared__ unsigned short T[64][72];
    int h = blockIdx.x, half = blockIdx.y;
    int t = threadIdx.x;
    const unsigned short* km = kmat + ((size_t)layer * H + h) * 64;
    {   // build lower-triangular Toeplitz T[l][j] = k[l-j]
        int l = t >> 2, j0 = (t & 3) * 16;
#pragma unroll
        for (int g = 0; g < 2; g++) {
            short8 v;
#pragma unroll
            for (int e = 0; e < 8; e++) {
                int j = j0 + g * 8 + e;
                v[e] = (j <= l) ? (short)km[l - j] : (short)0;
            }
            *reinterpret_cast<short8*>(&T[l][j0 + g * 8]) = v;
        }
    }
    __syncthreads();
    int wave = t >> 6, lane = t & 63;
    int r16 = lane & 15, quad = lane >> 4;
    const unsigned short* uh = ut + (size_t)h * BT;
    const unsigned short* vh = Vl + (size_t)h * 64 * 64;
    const unsigned short* eh = Sent + (size_t)h * NCC * 64;
    unsigned short* yh = yt + (size_t)h * BT;
    float Dh = Dp[layer * H + h];
    for (int nt = 0; nt < 4; nt++) {
        int cc0 = half * 256 + wave * 64 + nt * 16;
        float4v acc[4] = {};
#pragma unroll
        for (int k0 = 0; k0 < 64; k0 += 32) {    // Toeplitz part
            short8 bf = *reinterpret_cast<const short8*>(uh + (size_t)(cc0 + r16) * 64 + k0 + quad * 8);
#pragma unroll
            for (int mt = 0; mt < 4; mt++) {
                short8 af = *reinterpret_cast<const short8*>(&T[mt * 16 + r16][k0 + quad * 8]);
                acc[mt] = __builtin_amdgcn_mfma_f32_16x16x32_bf16(af, bf, acc[mt], 0, 0, 0);
            }
        }
#pragma unroll
        for (int k0 = 0; k0 < 64; k0 += 32) {    // entering-state correction
            short8 bf = *reinterpret_cast<const short8*>(eh + (size_t)(cc0 + r16) * 64 + k0 + quad * 8);
#pragma unroll
            for (int mt = 0; mt < 4; mt++) {
                short8 af = *reinterpret_cast<const short8*>(vh + (mt * 16 + r16) * 64 + k0 + quad * 8);
                acc[mt] = __builtin_amdgcn_mfma_f32_16x16x32_bf16(af, bf, acc[mt], 0, 0, 0);
            }
        }
        int cc = cc0 + r16;
#pragma unroll
        for (int mt = 0; mt < 4; mt++) {
            size_t p = (size_t)cc * 64 + mt * 16 + quad * 4;
            ushort4 uu = *(const ushort4*)(uh + p);
            float o[4];
#pragma unroll
            for (int r = 0; r < 4; r++) {
                float y = acc[mt][r] + Dh * bf2f(((const unsigned short*)&uu)[r]);
                o[r] = 0.5f * y * (1.0f + erff(y * 0.70710678118654752f));
            }
            *(uint2*)(yh + p) = pack4bf(o[0], o[1], o[2], o[3]);
        }
    }
}

// ---------- transpose y_t (H,BT bf16) -> ybf (BT,H bf16) ----------
__global__ __launch_bounds__(256) void transpose2_kernel(const unsigned short* __restrict__ yt,
                                                         unsigned short* __restrict__ yb) {
    __shared__ unsigned short tile[64][72];
    int bx = blockIdx.x;
    int pt = bx & 511, ht = bx >> 9;
    int p0 = pt * 64, h0 = ht * 64;
    int t = threadIdx.x;
    int jr = t & 7, ib = t >> 3;
#pragma unroll
    for (int pass = 0; pass < 2; pass++) {
        int i = ib + pass * 32;
        short8 v = *reinterpret_cast<const short8*>(yt + (size_t)(h0 + i) * BT + p0 + jr * 8);
#pragma unroll
        for (int e = 0; e < 8; e++) tile[i][jr * 8 + e] = (unsigned short)v[e];
    }
    __syncthreads();
    int pp = t >> 2, hg = t & 3;
    short8 o0, o1;
#pragma unroll
    for (int r = 0; r < 8; r++) o0[r] = (short)tile[hg * 16 + r][pp];
#pragma unroll
    for (int r = 0; r < 8; r++) o1[r] = (short)tile[hg * 16 + 8 + r][pp];
    unsigned short* dst = yb + (size_t)(p0 + pp) * H + h0 + hg * 16;
    *reinterpret_cast<short8*>(dst) = o0;
    *reinterpret_cast<short8*>(dst + 8) = o1;
}

// ---------- fused 1x1 conv + bias + GLU ----------
// v3: A-only in LDS (triple-buffered, counted vmcnt); W fragments loaded DIRECTLY from
// global (L2-resident slab) into double-buffered register sets via position-pinned asm
// loads. DS traffic per block-K-step halves (48KB -> 24KB): attacks the LDS-pipe bound.
// LDS chunk (row r, c) holds global chunk (r, c ^ ((r>>1)&3)); reads use the inverse.
__global__ __launch_bounds__(256) void gemm_glu_kernel(const unsigned short* __restrict__ ybf,
                                                       const unsigned short* __restrict__ Wbf,
                                                       const float* __restrict__ bias,
                                                       unsigned short* __restrict__ yo, int layer) {
    __shared__ unsigned short As[3][128 * 32];
    int tid = threadIdx.x;
    int wave = tid >> 6, lane = tid & 63;
    int wr = wave >> 1, wc = wave & 1;
    int r16 = lane & 15, quad = lane >> 4;
    int m0 = blockIdx.x * 128;
    int o0 = blockIdx.y * 64;
    const unsigned short* Wl = Wbf + (size_t)layer * 2 * H * H;

    // A staging: lane -> LDS row lane>>2, chunk lane&3; source col chunk is XOR-swizzled
    int srow = lane >> 2;
    int scol = ((lane & 3) ^ ((srow >> 1) & 3)) * 8;
    const unsigned short* aS0 = ybf + ((size_t)(m0 + wave * 16 + srow)) * H + scol;
    const unsigned short* aS1 = aS0 + (size_t)64 * H;
    const int aoff0 = (wave * 16) * 32;          // wave-uniform LDS dest offsets
    const int aoff1 = (64 + wave * 16) * 32;

    int rcol = (quad ^ ((r16 >> 1) & 3)) * 8;   // swizzled fragment column

    // W fragment pointers (per lane, 16B each; same lane->element mapping as the old
    // LDS path after unswizzle: row o, k-chunk quad)
    const unsigned short* wA0 = Wl + (size_t)(o0 + wc * 32 +  0 + r16) * H + quad * 8;
    const unsigned short* wA1 = Wl + (size_t)(o0 + wc * 32 + 16 + r16) * H + quad * 8;
    const unsigned short* wG0 = wA0 + (size_t)512 * H;
    const unsigned short* wG1 = wA1 + (size_t)512 * H;

    // double-buffered W register sets
    short8 wa0[2], wa1[2], wg0[2], wg1[2];

    float4v acc_a[4][2] = {}, acc_g[4][2] = {};

    // ---- prologue: A0(2) W0(4) A1(2); wait vmcnt(2) -> A0,W0 done, A1 in flight ----
    async_copy16(aS0, &As[0][aoff0]);
    async_copy16(aS1, &As[0][aoff1]);
    gload16(&wa0[0], wA0);
    gload16(&wa1[0], wA1);
    gload16(&wg0[0], wG0);
    gload16(&wg1[0], wG1);
    async_copy16(aS0 + 32, &As[1][aoff0]);
    async_copy16(aS1 + 32, &As[1][aoff1]);
    asm volatile("s_waitcnt vmcnt(2)" ::: "memory");
    __builtin_amdgcn_sched_barrier(0);
    __builtin_amdgcn_s_barrier();

#pragma unroll
    for (int ks = 0; ks < 16; ++ks) {
        const int b = ks % 3;
        const int cur = ks & 1, nxt = (ks + 1) & 1;
        // issue W[ks+1] (4) then A[ks+2] (2); boundary vmcnt(2) retires {A[ks+1],W[ks+1]}
        if (ks < 15) {
            const int kw = (ks + 1) * 32;
            gload16(&wa0[nxt], wA0 + kw);
            gload16(&wa1[nxt], wA1 + kw);
            gload16(&wg0[nxt], wG0 + kw);
            gload16(&wg1[nxt], wG1 + kw);
        }
        if (ks < 14) {
            const int nb = (ks + 2) % 3;
            const int kn = (ks + 2) * 32;
            async_copy16(aS0 + kn, &As[nb][aoff0]);
            async_copy16(aS1 + kn, &As[nb][aoff1]);
        }

        short8 af[4];
#pragma unroll
        for (int mi = 0; mi < 4; mi++)
            af[mi] = *reinterpret_cast<const short8*>(&As[b][(wr * 64 + mi * 16 + r16) * 32 + rcol]);
#pragma unroll
        for (int mi = 0; mi < 4; mi++) {
            acc_a[mi][0] = __builtin_amdgcn_mfma_f32_16x16x32_bf16(af[mi], wa0[cur], acc_a[mi][0], 0, 0, 0);
            acc_a[mi][1] = __builtin_amdgcn_mfma_f32_16x16x32_bf16(af[mi], wa1[cur], acc_a[mi][1], 0, 0, 0);
            acc_g[mi][0] = __builtin_amdgcn_mfma_f32_16x16x32_bf16(af[mi], wg0[cur], acc_g[mi][0], 0, 0, 0);
            acc_g[mi][1] = __builtin_amdgcn_mfma_f32_16x16x32_bf16(af[mi], wg1[cur], acc_g[mi][1], 0, 0, 0);
        }

        // boundary: my LDS reads done (lgkm), {A[ks+1],W[ks+1]} retired (vmcnt), all waves synced
        if (ks < 14) {
            asm volatile("s_waitcnt vmcnt(2) lgkmcnt(0)" ::: "memory");
            __builtin_amdgcn_sched_barrier(0);
            __builtin_amdgcn_s_barrier();
        } else if (ks == 14) {
            asm volatile("s_waitcnt vmcnt(0) lgkmcnt(0)" ::: "memory");
            __builtin_amdgcn_sched_barrier(0);
            __builtin_amdgcn_s_barrier();
        }
    }

    const float* bl = bias + layer * 2 * H;
#pragma unroll
    for (int ni = 0; ni < 2; ni++) {
        int o = o0 + wc * 32 + ni * 16 + r16;
        float ba_ = bl[o], bg_ = bl[H + o];
#pragma unroll
        for (int mi = 0; mi < 4; mi++)
#pragma unroll
            for (int r = 0; r < 4; r++) {
                int l = m0 + wr * 64 + mi * 16 + quad * 4 + r;
                float av = acc_a[mi][ni][r] + ba_;
                float gv = acc_g[mi][ni][r] + bg_;
                yo[(size_t)l * H + o] = f2bf(av * (1.0f / (1.0f + expf(-gv))));
            }
    }
}

// ---------- residual + LayerNorm (bf16 residual stream; final layer fp32) ----------
__global__ __launch_bounds__(256) void ln_kernel(const unsigned short* __restrict__ yo,
                                                 const float* __restrict__ xf,
                                                 const unsigned short* __restrict__ xb,
                                                 const float* __restrict__ gamma, const float* __restrict__ beta,
                                                 float* __restrict__ of, unsigned short* __restrict__ ob,
                                                 int in_f32, int out_f32, int layer) {
    int wave = threadIdx.x >> 6, lane = threadIdx.x & 63;
    size_t row = (size_t)blockIdx.x * 4 + wave;
    const unsigned short* yp = yo + row * H + lane * 8;
    short8 yv = *reinterpret_cast<const short8*>(yp);
    float v[8];
    if (in_f32) {
        const float* xp = xf + row * H + lane * 8;
        float4 x0 = *(const float4*)(xp);
        float4 x1 = *(const float4*)(xp + 4);
        v[0] = bf2f((unsigned short)yv[0]) + x0.x; v[1] = bf2f((unsigned short)yv[1]) + x0.y;
        v[2] = bf2f((unsigned short)yv[2]) + x0.z; v[3] = bf2f((unsigned short)yv[3]) + x0.w;
        v[4] = bf2f((unsigned short)yv[4]) + x1.x; v[5] = bf2f((unsigned short)yv[5]) + x1.y;
        v[6] = bf2f((unsigned short)yv[6]) + x1.z; v[7] = bf2f((unsigned short)yv[7]) + x1.w;
    } else {
        const unsigned short* xp = xb + row * H + lane * 8;
        short8 xv = *reinterpret_cast<const short8*>(xp);
#pragma unroll
        for (int i = 0; i < 8; i++)
            v[i] = bf2f((unsigned short)yv[i]) + bf2f((unsigned short)xv[i]);
    }
    float s = 0.f, s2 = 0.f;
#pragma unroll
    for (int i = 0; i < 8; i++) { s += v[i]; s2 = fmaf(v[i], v[i], s2); }
#pragma unroll
    for (int off = 32; off; off >>= 1) {
        s += __shfl_xor(s, off);
        s2 += __shfl_xor(s2, off);
    }
    float mu = s * (1.0f / H);
    float var = s2 * (1.0f / H) - mu * mu;
    float inv = rsqrtf(var + 1e-5f);
    const float* gl = gamma + layer * H + lane * 8;
    const float* bl = beta + layer * H + lane * 8;
    float o[8];
#pragma unroll
    for (int i = 0; i < 8; i++)
        o[i] = (v[i] - mu) * inv * gl[i] + bl[i];
    if (out_f32) {
        float* op = of + row * H + lane * 8;
        *(float4*)(op) = make_float4(o[0], o[1], o[2], o[3]);
        *(float4*)(op + 4) = make_float4(o[4], o[5], o[6], o[7]);
    } else {
        unsigned short* op = ob + row * H + lane * 8;
        uint2 p0 = pack4bf(o[0], o[1], o[2], o[3]);
        uint2 p1 = pack4bf(o[4], o[5], o[6], o[7]);
        *(uint2*)(op) = p0;
        *(uint2*)(op + 4) = p1;
    }
}

extern "C" void kernel_launch(void* const* d_in, const int* in_sizes, int n_in,
                              void* d_out, int out_size, void* d_ws, size_t ws_size,
                              hipStream_t stream) {
    const float* x          = (const float*)d_in[0];
    const float* log_dt     = (const float*)d_in[1];
    const float* A_imag     = (const float*)d_in[2];
    const float* log_A_real = (const float*)d_in[3];
    const float* C          = (const float*)d_in[4];
    const float* D          = (const float*)d_in[5];
    const float* W          = (const float*)d_in[6];
    const float* bias       = (const float*)d_in[7];
    const float* gamma      = (const float*)d_in[8];
    const float* beta       = (const float*)d_in[9];

    char* ws = (char*)d_ws;
    unsigned short* xR   = (unsigned short*)(ws + 0);           // bf16 residual stream
    unsigned short* Sloc = (unsigned short*)(ws + 67108864);
    unsigned short* u_t  = (unsigned short*)(ws + 100663296);
    unsigned short* ybf  = (unsigned short*)(ws + 100663296);   // overlay: after conv, u_t dead
    unsigned short* y_t  = (unsigned short*)(ws + 134217728);
    unsigned short* yo   = (unsigned short*)(ws + 134217728);   // overlay: after transpose2, y_t dead
    unsigned short* Wbf  = (unsigned short*)(ws + 167772160);
    unsigned short* WV   = (unsigned short*)(ws + 171966464);   // Wstate then V per layer
    unsigned short* kmat = (unsigned short*)(ws + 176160768);
    float*          dA   = (float*)(ws + 176422912);
    float*          Ct   = (float*)(ws + 176947200);
    float* xout_final    = (float*)d_out;

    wconv_kernel<<<NL * 2 * H * H / 256, 256, 0, stream>>>(W, Wbf);
    params_kernel<<<NL * N2 * H / 256, 256, 0, stream>>>(log_dt, A_imag, log_A_real, C, dA, Ct);
    kergen_k_kernel<<<NL * H * 64 / 256, 256, 0, stream>>>(dA, Ct, kmat);

    for (int layer = 0; layer < NL; ++layer) {
        if (layer == 0)
            t1_f32_kernel<<<4096, 256, 0, stream>>>(x, u_t);
        else
            t1_bf16_kernel<<<4096, 256, 0, stream>>>(xR, u_t);
        kergenW_kernel<<<H * 64 * 64 / 256, 256, 0, stream>>>(dA, WV, layer);
        states_kernel<<<H, 256, 0, stream>>>(u_t, WV, Sloc);
        combine_kernel<<<H * Bsz * N2 / 256, 256, 0, stream>>>(Sloc, dA, layer);
        kergenV_kernel<<<H * 64 * 64 / 256, 256, 0, stream>>>(dA, Ct, WV, layer);
        conv_kernel<<<dim3(H, 2), 256, 0, stream>>>(u_t, kmat, WV, Sloc, D, y_t, layer);
        transpose2_kernel<<<4096, 256, 0, stream>>>(y_t, ybf);
        gemm_glu_kernel<<<dim3(BT / 128, H / 64), 256, 0, stream>>>(ybf, Wbf, bias, yo, layer);
        int in_f32 = (layer == 0), out_f32 = (layer == NL - 1);
        ln_kernel<<<BT / 4, 256, 0, stream>>>(yo, x, xR, gamma, beta,
                                              xout_final, xR, in_f32, out_f32, layer);
    }
}

// Round 5
// 854.281 us; speedup vs baseline: 1.1188x; 1.1188x over previous
//
#include <hip/hip_runtime.h>
#include <hip/hip_bf16.h>
#include <math.h>

#define H 512
#define NL 4
#define N2 32
#define Bsz 8
#define Lseq 4096
#define BT (Bsz*Lseq)        // 32768 total positions
#define LC2 64               // chunk length
#define NCC (BT/LC2)         // 512 chunks total
#define CPB (Lseq/LC2)       // 64 chunks per batch element

typedef __attribute__((ext_vector_type(8))) short short8;   // 8 bf16
typedef __attribute__((ext_vector_type(4))) float float4v;

// ---------------- ws layout (bytes) ----------------
// 0         : xR   (bf16 BT*H residual)        33554432
// 67108864  : Sloc (bf16 H*NCC*64)             33554432
// 100663296 : u_t  (bf16 H*BT) / ybf overlay   33554432
// 134217728 : y_t  (bf16 H*BT) / yo overlay    33554432
// 167772160 : Wbf  (bf16 NL*2H*H)               4194304
// 171966464 : WV   (bf16 H*64*64, Wstate->V)    4194304
// 176160768 : kmat (bf16 NL*H*64)                262144
// 176422912 : dA   (fp32 NL*N2*2*H)              524288
// 176947200 : Ct   (fp32 NL*N2*2*H)              524288

__device__ __forceinline__ float bf2f(unsigned short u) {
    union { unsigned int i; float f; } x; x.i = ((unsigned int)u) << 16; return x.f;
}
__device__ __forceinline__ unsigned short f2bf(float f) {
    union { float f; unsigned int i; } x; x.f = f;
    unsigned int u = x.i + 0x7fff + ((x.i >> 16) & 1);
    return (unsigned short)(u >> 16);
}
__device__ __forceinline__ uint2 pack4bf(float a, float b, float c, float d) {
    uint2 r;
    r.x = (unsigned)f2bf(a) | ((unsigned)f2bf(b) << 16);
    r.y = (unsigned)f2bf(c) | ((unsigned)f2bf(d) << 16);
    return r;
}
__device__ __forceinline__ void async_copy16(const void* g, void* l) {
    __builtin_amdgcn_global_load_lds(
        (const __attribute__((address_space(1))) void*)g,
        (__attribute__((address_space(3))) void*)l, 16, 0, 0);
}

// ---------- convert W to bf16 ----------
__global__ void wconv_kernel(const float* __restrict__ W, unsigned short* __restrict__ Wbf) {
    int tid = blockIdx.x * 256 + threadIdx.x;
    Wbf[tid] = f2bf(W[tid]);
}

// ---------- per-(layer,n,h): dA = log(lambda), Ct = 2C(lambda-1)/A ----------
__global__ void params_kernel(const float* __restrict__ log_dt, const float* __restrict__ A_imag,
                              const float* __restrict__ log_A_real, const float* __restrict__ Cin,
                              float* __restrict__ dA, float* __restrict__ Ct) {
    int tid = blockIdx.x * 256 + threadIdx.x;   // ((layer*N2+n)*H + h)
    int h = tid % H;
    int n = (tid / H) % N2;
    int layer = tid / (H * N2);
    float dt = expf(log_dt[layer * H + h]);
    int pidx = (layer * H + h) * N2 + n;
    float Are = -expf(log_A_real[pidx]);
    float Aim = A_imag[pidx];
    float dre = Are * dt, dim = Aim * dt;
    float er = expf(dre);
    float lre = er * cosf(dim), lim = er * sinf(dim);
    float nre = lre - 1.0f, nim = lim;
    float inv = 1.0f / (Are * Are + Aim * Aim);
    float tre = (nre * Are + nim * Aim) * inv;
    float tim = (nim * Are - nre * Aim) * inv;
    float Ccre = Cin[pidx * 2], Ccim = Cin[pidx * 2 + 1];
    int oidx = ((layer * N2 + n) * 2) * H + h;
    dA[oidx] = dre;  dA[oidx + H] = dim;
    Ct[oidx] = 2.0f * (Ccre * tre - Ccim * tim);
    Ct[oidx + H] = 2.0f * (Ccre * tim + Ccim * tre);
}

// ---------- kernels k[d] = Re sum_n Ct_n lambda_n^d, all layers ----------
__global__ void kergen_k_kernel(const float* __restrict__ dA, const float* __restrict__ Ct,
                                unsigned short* __restrict__ kmat) {
    int t = blockIdx.x * 256 + threadIdx.x;     // (layer*H + h)*64 + d
    int d = t & 63;
    int h = (t >> 6) & (H - 1);
    int layer = t >> 15;
    float fd = (float)d;
    float sum = 0.f;
    for (int n = 0; n < N2; n++) {
        int base = ((layer * N2 + n) * 2) * H + h;
        float dre = dA[base], dim = dA[base + H];
        float Ctr = Ct[base], Cti = Ct[base + H];
        float e = expf(dre * fd);
        sum += Ctr * e * cosf(dim * fd) - Cti * e * sinf(dim * fd);
    }
    kmat[t] = f2bf(sum);
}

// ---------- Wstate[h][r][j]: r=2n -> Re(l^(63-j)), r=2n+1 -> Im ----------
__global__ void kergenW_kernel(const float* __restrict__ dA, unsigned short* __restrict__ Wst, int layer) {
    int t = blockIdx.x * 256 + threadIdx.x;     // (h*64 + r)*64 + j
    int j = t & 63;
    int r = (t >> 6) & 63;
    int h = t >> 12;
    int n = r >> 1;
    int base = ((layer * N2 + n) * 2) * H + h;
    float dre = dA[base], dim = dA[base + H];
    float p = (float)(63 - j);
    float e = expf(dre * p);
    Wst[t] = f2bf((r & 1) ? e * sinf(dim * p) : e * cosf(dim * p));
}

// ---------- V[h][l][c2]: c2=2n -> Re(Ct l^(l+1)), c2=2n+1 -> -Im ----------
__global__ void kergenV_kernel(const float* __restrict__ dA, const float* __restrict__ Ct,
                               unsigned short* __restrict__ Vl, int layer) {
    int t = blockIdx.x * 256 + threadIdx.x;     // (h*64 + l)*64 + c2
    int c2 = t & 63;
    int l = (t >> 6) & 63;
    int h = t >> 12;
    int n = c2 >> 1;
    int base = ((layer * N2 + n) * 2) * H + h;
    float dre = dA[base], dim = dA[base + H];
    float Ctr = Ct[base], Cti = Ct[base + H];
    float q = (float)(l + 1);
    float e = expf(dre * q);
    float ar = e * cosf(dim * q), ai = e * sinf(dim * q);
    float vre = Ctr * ar - Cti * ai;
    float vim = Ctr * ai + Cti * ar;
    Vl[t] = f2bf((c2 & 1) ? -vim : vre);
}

// ---------- transpose x fp32 (BT,H) -> u_t bf16 (H,BT)  [layer 0 only] ----------
__global__ __launch_bounds__(256) void t1_f32_kernel(const float* __restrict__ xi,
                                                     unsigned short* __restrict__ ut) {
    __shared__ float tile[64][68];
    int bx = blockIdx.x;
    int pt = bx & 511, ht = bx >> 9;
    int p0 = pt * 64, h0 = ht * 64;
    int t = threadIdx.x;
    int jr = t & 15, ib = t >> 4;
#pragma unroll
    for (int pass = 0; pass < 4; pass++) {
        int i = ib + pass * 16;
        float4 v = *(const float4*)(xi + (size_t)(p0 + i) * H + h0 + jr * 4);
        *(float4*)(&tile[i][jr * 4]) = v;   // 272B row stride -> 16B aligned
    }
    __syncthreads();
#pragma unroll
    for (int pass = 0; pass < 4; pass++) {
        int i2 = ib + pass * 16;
        int j2 = jr * 4;
        uint2 pk = pack4bf(tile[j2][i2], tile[j2 + 1][i2], tile[j2 + 2][i2], tile[j2 + 3][i2]);
        *(uint2*)(ut + (size_t)(h0 + i2) * BT + p0 + j2) = pk;
    }
}

// ---------- local chunk states: Sloc[h][cc][r] = sum_j Wst[r][j] u[cc*64+j] ----------
__global__ __launch_bounds__(256) void states_kernel(const unsigned short* __restrict__ ut,
                                                     const unsigned short* __restrict__ Wst,
                                                     unsigned short* __restrict__ Sloc) {
    int h = blockIdx.x;
    int wave = threadIdx.x >> 6, lane = threadIdx.x & 63;
    int r16 = lane & 15, quad = lane >> 4;
    const unsigned short* uh = ut + (size_t)h * BT;
    const unsigned short* wh = Wst + (size_t)h * 64 * 64;
    unsigned short* sh = Sloc + (size_t)h * NCC * 64;
    for (int nt = 0; nt < 8; nt++) {
        int cc0 = wave * 128 + nt * 16;
        float4v acc[4] = {};
#pragma unroll
        for (int k0 = 0; k0 < 64; k0 += 32) {
            short8 bf = *reinterpret_cast<const short8*>(uh + (size_t)(cc0 + r16) * 64 + k0 + quad * 8);
#pragma unroll
            for (int mt = 0; mt < 4; mt++) {
                short8 af = *reinterpret_cast<const short8*>(wh + (mt * 16 + r16) * 64 + k0 + quad * 8);
                acc[mt] = __builtin_amdgcn_mfma_f32_16x16x32_bf16(af, bf, acc[mt], 0, 0, 0);
            }
        }
        int cc = cc0 + r16;
#pragma unroll
        for (int mt = 0; mt < 4; mt++) {
            uint2 pk = pack4bf(acc[mt][0], acc[mt][1], acc[mt][2], acc[mt][3]);
            *(uint2*)(sh + (size_t)cc * 64 + mt * 16 + quad * 4) = pk;
        }
    }
}

// ---------- combine: in-place scan over chunks; Sloc becomes ENTERING state ----------
__global__ void combine_kernel(unsigned short* __restrict__ Sloc, const float* __restrict__ dA, int layer) {
    int t = blockIdx.x * 256 + threadIdx.x;     // n(32) | b(8) | h(512)
    int n = t & 31;
    int b = (t >> 5) & 7;
    int h = t >> 8;
    int base = ((layer * N2 + n) * 2) * H + h;
    float dre = dA[base], dim = dA[base + H];
    float e = expf(dre * 64.f);
    float Lr = e * cosf(dim * 64.f), Li = e * sinf(dim * 64.f);
    unsigned int* p = (unsigned int*)Sloc + ((size_t)h * NCC + b * CPB) * 32 + n;
    float sr = 0.f, si = 0.f;
    for (int c = 0; c < CPB; c++) {
        unsigned int v = p[(size_t)c * 32];
        float pr = bf2f(v & 0xffff), pi = bf2f(v >> 16);
        p[(size_t)c * 32] = (unsigned)f2bf(sr) | ((unsigned)f2bf(si) << 16);
        float nr = fmaf(Lr, sr, fmaf(-Li, si, pr));
        float ni = fmaf(Lr, si, fmaf(Li, sr, pi));
        sr = nr; si = ni;
    }
}

// ---------- conv: Toeplitz GEMM + state-correction GEMM + D*u + gelu -> y_t ----------
__global__ __launch_bounds__(256) void conv_kernel(const unsigned short* __restrict__ ut,
                                                   const unsigned short* __restrict__ kmat,
                                                   const unsigned short* __restrict__ Vl,
                                                   const unsigned short* __restrict__ Sent,
                                                   const float* __restrict__ Dp,
                                                   unsigned short* __restrict__ yt, int layer) {
    __shared__ unsigned short T[64][72];
    int h = blockIdx.x, half = blockIdx.y;
    int t = threadIdx.x;
    const unsigned short* km = kmat + ((size_t)layer * H + h) * 64;
    {   // build lower-triangular Toeplitz T[l][j] = k[l-j]
        int l = t >> 2, j0 = (t & 3) * 16;
#pragma unroll
        for (int g = 0; g < 2; g++) {
            short8 v;
#pragma unroll
            for (int e = 0; e < 8; e++) {
                int j = j0 + g * 8 + e;
                v[e] = (j <= l) ? (short)km[l - j] : (short)0;
            }
            *reinterpret_cast<short8*>(&T[l][j0 + g * 8]) = v;
        }
    }
    __syncthreads();
    int wave = t >> 6, lane = t & 63;
    int r16 = lane & 15, quad = lane >> 4;
    const unsigned short* uh = ut + (size_t)h * BT;
    const unsigned short* vh = Vl + (size_t)h * 64 * 64;
    const unsigned short* eh = Sent + (size_t)h * NCC * 64;
    unsigned short* yh = yt + (size_t)h * BT;
    float Dh = Dp[layer * H + h];
    for (int nt = 0; nt < 4; nt++) {
        int cc0 = half * 256 + wave * 64 + nt * 16;
        float4v acc[4] = {};
#pragma unroll
        for (int k0 = 0; k0 < 64; k0 += 32) {    // Toeplitz part
            short8 bf = *reinterpret_cast<const short8*>(uh + (size_t)(cc0 + r16) * 64 + k0 + quad * 8);
#pragma unroll
            for (int mt = 0; mt < 4; mt++) {
                short8 af = *reinterpret_cast<const short8*>(&T[mt * 16 + r16][k0 + quad * 8]);
                acc[mt] = __builtin_amdgcn_mfma_f32_16x16x32_bf16(af, bf, acc[mt], 0, 0, 0);
            }
        }
#pragma unroll
        for (int k0 = 0; k0 < 64; k0 += 32) {    // entering-state correction
            short8 bf = *reinterpret_cast<const short8*>(eh + (size_t)(cc0 + r16) * 64 + k0 + quad * 8);
#pragma unroll
            for (int mt = 0; mt < 4; mt++) {
                short8 af = *reinterpret_cast<const short8*>(vh + (mt * 16 + r16) * 64 + k0 + quad * 8);
                acc[mt] = __builtin_amdgcn_mfma_f32_16x16x32_bf16(af, bf, acc[mt], 0, 0, 0);
            }
        }
        int cc = cc0 + r16;
#pragma unroll
        for (int mt = 0; mt < 4; mt++) {
            size_t p = (size_t)cc * 64 + mt * 16 + quad * 4;
            ushort4 uu = *(const ushort4*)(uh + p);
            float o[4];
#pragma unroll
            for (int r = 0; r < 4; r++) {
                float y = acc[mt][r] + Dh * bf2f(((const unsigned short*)&uu)[r]);
                o[r] = 0.5f * y * (1.0f + erff(y * 0.70710678118654752f));
            }
            *(uint2*)(yh + p) = pack4bf(o[0], o[1], o[2], o[3]);
        }
    }
}

// ---------- transpose y_t (H,BT bf16) -> ybf (BT,H bf16) ----------
__global__ __launch_bounds__(256) void transpose2_kernel(const unsigned short* __restrict__ yt,
                                                         unsigned short* __restrict__ yb) {
    __shared__ unsigned short tile[64][72];
    int bx = blockIdx.x;
    int pt = bx & 511, ht = bx >> 9;
    int p0 = pt * 64, h0 = ht * 64;
    int t = threadIdx.x;
    int jr = t & 7, ib = t >> 3;
#pragma unroll
    for (int pass = 0; pass < 2; pass++) {
        int i = ib + pass * 32;
        short8 v = *reinterpret_cast<const short8*>(yt + (size_t)(h0 + i) * BT + p0 + jr * 8);
        *reinterpret_cast<short8*>(&tile[i][jr * 8]) = v;   // 144B row stride -> 16B aligned
    }
    __syncthreads();
    int pp = t >> 2, hg = t & 3;
    short8 o0, o1;
#pragma unroll
    for (int r = 0; r < 8; r++) o0[r] = (short)tile[hg * 16 + r][pp];
#pragma unroll
    for (int r = 0; r < 8; r++) o1[r] = (short)tile[hg * 16 + 8 + r][pp];
    unsigned short* dst = yb + (size_t)(p0 + pp) * H + h0 + hg * 16;
    *reinterpret_cast<short8*>(dst) = o0;
    *reinterpret_cast<short8*>(dst + 8) = o1;
}

// ---------- fused 1x1 conv (LDS-tiled, bank-conflict-free swizzle) + bias + GLU ----------
// v2 (proven): triple-buffered LDS, depth-2 prefetch, raw s_barrier + counted vmcnt.
// LDS chunk (row r, c) holds global chunk (r, c ^ ((r>>1)&3)); reads use the inverse.
__global__ __launch_bounds__(256) void gemm_glu_kernel(const unsigned short* __restrict__ ybf,
                                                       const unsigned short* __restrict__ Wbf,
                                                       const float* __restrict__ bias,
                                                       unsigned short* __restrict__ yo, int layer) {
    __shared__ unsigned short As[3][128 * 32];
    __shared__ unsigned short Bs[3][128 * 32];
    int tid = threadIdx.x;
    int wave = tid >> 6, lane = tid & 63;
    int wr = wave >> 1, wc = wave & 1;
    int r16 = lane & 15, quad = lane >> 4;
    int m0 = blockIdx.x * 128;
    int o0 = blockIdx.y * 64;
    const unsigned short* Wl = Wbf + (size_t)layer * 2 * H * H;

    // staging: lane -> LDS row lane>>2, chunk lane&3; source col chunk is XOR-swizzled
    int srow = lane >> 2;
    int scol = ((lane & 3) ^ ((srow >> 1) & 3)) * 8;
    const unsigned short* aS0 = ybf + ((size_t)(m0 + wave * 16 + srow)) * H + scol;
    const unsigned short* aS1 = aS0 + (size_t)64 * H;
    const unsigned short* bSA = Wl + ((size_t)(o0 + wave * 16 + srow)) * H + scol;
    const unsigned short* bSG = bSA + (size_t)512 * H;
    const int aoff0 = (wave * 16) * 32;          // wave-uniform LDS dest offsets
    const int aoff1 = (64 + wave * 16) * 32;

    int rcol = (quad ^ ((r16 >> 1) & 3)) * 8;   // swizzled fragment column

    float4v acc_a[4][2] = {}, acc_g[4][2] = {};

    // ---- prologue: prefetch K-steps 0 and 1 into buffers 0 and 1 ----
    async_copy16(aS0,      &As[0][aoff0]);
    async_copy16(aS1,      &As[0][aoff1]);
    async_copy16(bSA,      &Bs[0][aoff0]);
    async_copy16(bSG,      &Bs[0][aoff1]);
    async_copy16(aS0 + 32, &As[1][aoff0]);
    async_copy16(aS1 + 32, &As[1][aoff1]);
    async_copy16(bSA + 32, &Bs[1][aoff0]);
    async_copy16(bSG + 32, &Bs[1][aoff1]);
    asm volatile("s_waitcnt vmcnt(4)" ::: "memory");   // buffer 0 landed
    __builtin_amdgcn_s_barrier();

#pragma unroll
    for (int ks = 0; ks < 16; ++ks) {
        const int b = ks % 3;
        if (ks < 14) {   // issue depth-2 prefetch BEFORE compute; overwrites buf read at ks-1
            const int nb = (ks + 2) % 3;
            const int kn = (ks + 2) * 32;
            async_copy16(aS0 + kn, &As[nb][aoff0]);
            async_copy16(aS1 + kn, &As[nb][aoff1]);
            async_copy16(bSA + kn, &Bs[nb][aoff0]);
            async_copy16(bSG + kn, &Bs[nb][aoff1]);
        }

        short8 af[4], ba[2], bg[2];
#pragma unroll
        for (int mi = 0; mi < 4; mi++)
            af[mi] = *reinterpret_cast<const short8*>(&As[b][(wr * 64 + mi * 16 + r16) * 32 + rcol]);
#pragma unroll
        for (int ni = 0; ni < 2; ni++) {
            ba[ni] = *reinterpret_cast<const short8*>(&Bs[b][(wc * 32 + ni * 16 + r16) * 32 + rcol]);
            bg[ni] = *reinterpret_cast<const short8*>(&Bs[b][(64 + wc * 32 + ni * 16 + r16) * 32 + rcol]);
        }
#pragma unroll
        for (int mi = 0; mi < 4; mi++)
#pragma unroll
            for (int ni = 0; ni < 2; ni++) {
                acc_a[mi][ni] = __builtin_amdgcn_mfma_f32_16x16x32_bf16(af[mi], ba[ni], acc_a[mi][ni], 0, 0, 0);
                acc_g[mi][ni] = __builtin_amdgcn_mfma_f32_16x16x32_bf16(af[mi], bg[ni], acc_g[mi][ni], 0, 0, 0);
            }

        // boundary: all my LDS reads done; oldest prefetch (next buffer) landed; all waves synced.
        if (ks < 14) {
            asm volatile("s_waitcnt vmcnt(4) lgkmcnt(0)" ::: "memory");
            __builtin_amdgcn_s_barrier();
        } else if (ks == 14) {
            asm volatile("s_waitcnt vmcnt(0) lgkmcnt(0)" ::: "memory");
            __builtin_amdgcn_s_barrier();
        }
    }

    const float* bl = bias + layer * 2 * H;
#pragma unroll
    for (int ni = 0; ni < 2; ni++) {
        int o = o0 + wc * 32 + ni * 16 + r16;
        float ba_ = bl[o], bg_ = bl[H + o];
#pragma unroll
        for (int mi = 0; mi < 4; mi++)
#pragma unroll
            for (int r = 0; r < 4; r++) {
                int l = m0 + wr * 64 + mi * 16 + quad * 4 + r;
                float av = acc_a[mi][ni][r] + ba_;
                float gv = acc_g[mi][ni][r] + bg_;
                yo[(size_t)l * H + o] = f2bf(av * (1.0f / (1.0f + expf(-gv))));
            }
    }
}

// ---------- fused residual + LayerNorm + transpose-out (layers 0..2) ----------
// Block: 64 positions x 512 h. Writes xR (BT,H) AND u_t (H,BT) for the next layer,
// eliminating the separate t1_bf16 transpose kernel (saves a 64MB global round trip).
__global__ __launch_bounds__(256) void ln_t_kernel(const unsigned short* __restrict__ yo,
                                                   const float* __restrict__ xf,
                                                   const unsigned short* __restrict__ xb,
                                                   const float* __restrict__ gamma,
                                                   const float* __restrict__ beta,
                                                   unsigned short* __restrict__ xR,
                                                   unsigned short* __restrict__ ut,
                                                   int in_f32, int layer) {
    __shared__ unsigned short tl[64][520];   // [p-local][h]; 1040B row stride (16B aligned)
    int t = threadIdx.x;
    int p0 = blockIdx.x * 64;
    int lane8 = t & 7;          // 8 lanes share one row
    int rowb = t >> 3;          // 0..31
    const float* gl = gamma + layer * H;
    const float* bl = beta + layer * H;
#pragma unroll
    for (int rr = 0; rr < 2; rr++) {
        int row = rowb + rr * 32;
        size_t gbase = (size_t)(p0 + row) * H;
        float v[64];
        float s = 0.f, s2 = 0.f;
#pragma unroll
        for (int cc = 0; cc < 8; cc++) {
            int h0 = (lane8 + cc * 8) * 8;
            short8 yv = *reinterpret_cast<const short8*>(yo + gbase + h0);
            if (in_f32) {
                float4 x0 = *(const float4*)(xf + gbase + h0);
                float4 x1 = *(const float4*)(xf + gbase + h0 + 4);
                v[cc * 8 + 0] = bf2f((unsigned short)yv[0]) + x0.x;
                v[cc * 8 + 1] = bf2f((unsigned short)yv[1]) + x0.y;
                v[cc * 8 + 2] = bf2f((unsigned short)yv[2]) + x0.z;
                v[cc * 8 + 3] = bf2f((unsigned short)yv[3]) + x0.w;
                v[cc * 8 + 4] = bf2f((unsigned short)yv[4]) + x1.x;
                v[cc * 8 + 5] = bf2f((unsigned short)yv[5]) + x1.y;
                v[cc * 8 + 6] = bf2f((unsigned short)yv[6]) + x1.z;
                v[cc * 8 + 7] = bf2f((unsigned short)yv[7]) + x1.w;
            } else {
                short8 xv = *reinterpret_cast<const short8*>(xb + gbase + h0);
#pragma unroll
                for (int i = 0; i < 8; i++)
                    v[cc * 8 + i] = bf2f((unsigned short)yv[i]) + bf2f((unsigned short)xv[i]);
            }
#pragma unroll
            for (int i = 0; i < 8; i++) { s += v[cc * 8 + i]; s2 = fmaf(v[cc * 8 + i], v[cc * 8 + i], s2); }
        }
        // reduce across the 8 lanes owning this row (lane bits 0..2)
        s += __shfl_xor(s, 1);  s2 += __shfl_xor(s2, 1);
        s += __shfl_xor(s, 2);  s2 += __shfl_xor(s2, 2);
        s += __shfl_xor(s, 4);  s2 += __shfl_xor(s2, 4);
        float mu = s * (1.0f / H);
        float var = s2 * (1.0f / H) - mu * mu;
        float inv = rsqrtf(var + 1e-5f);
#pragma unroll
        for (int cc = 0; cc < 8; cc++) {
            int h0 = (lane8 + cc * 8) * 8;
            float4 g0 = *(const float4*)(gl + h0);
            float4 g1 = *(const float4*)(gl + h0 + 4);
            float4 b0 = *(const float4*)(bl + h0);
            float4 b1 = *(const float4*)(bl + h0 + 4);
            short8 pk;
            pk[0] = (short)f2bf((v[cc * 8 + 0] - mu) * inv * g0.x + b0.x);
            pk[1] = (short)f2bf((v[cc * 8 + 1] - mu) * inv * g0.y + b0.y);
            pk[2] = (short)f2bf((v[cc * 8 + 2] - mu) * inv * g0.z + b0.z);
            pk[3] = (short)f2bf((v[cc * 8 + 3] - mu) * inv * g0.w + b0.w);
            pk[4] = (short)f2bf((v[cc * 8 + 4] - mu) * inv * g1.x + b1.x);
            pk[5] = (short)f2bf((v[cc * 8 + 5] - mu) * inv * g1.y + b1.y);
            pk[6] = (short)f2bf((v[cc * 8 + 6] - mu) * inv * g1.z + b1.z);
            pk[7] = (short)f2bf((v[cc * 8 + 7] - mu) * inv * g1.w + b1.w);
            *reinterpret_cast<short8*>(xR + gbase + h0) = pk;
            *reinterpret_cast<short8*>(&tl[row][h0]) = pk;
        }
    }
    __syncthreads();
    // transpose phase: thread handles h-rows t and t+256; per h write 128B contiguous
#pragma unroll
    for (int hh = 0; hh < 2; hh++) {
        int h = t + hh * 256;
        unsigned short* dst = ut + (size_t)h * BT + p0;
#pragma unroll
        for (int pc = 0; pc < 8; pc++) {
            short8 o;
#pragma unroll
            for (int e = 0; e < 8; e++) o[e] = (short)tl[pc * 8 + e][h];
            *reinterpret_cast<short8*>(dst + pc * 8) = o;
        }
    }
}

// ---------- residual + LayerNorm (final layer: fp32 out) ----------
__global__ __launch_bounds__(256) void ln_kernel(const unsigned short* __restrict__ yo,
                                                 const float* __restrict__ xf,
                                                 const unsigned short* __restrict__ xb,
                                                 const float* __restrict__ gamma, const float* __restrict__ beta,
                                                 float* __restrict__ of, unsigned short* __restrict__ ob,
                                                 int in_f32, int out_f32, int layer) {
    int wave = threadIdx.x >> 6, lane = threadIdx.x & 63;
    size_t row = (size_t)blockIdx.x * 4 + wave;
    const unsigned short* yp = yo + row * H + lane * 8;
    short8 yv = *reinterpret_cast<const short8*>(yp);
    float v[8];
    if (in_f32) {
        const float* xp = xf + row * H + lane * 8;
        float4 x0 = *(const float4*)(xp);
        float4 x1 = *(const float4*)(xp + 4);
        v[0] = bf2f((unsigned short)yv[0]) + x0.x; v[1] = bf2f((unsigned short)yv[1]) + x0.y;
        v[2] = bf2f((unsigned short)yv[2]) + x0.z; v[3] = bf2f((unsigned short)yv[3]) + x0.w;
        v[4] = bf2f((unsigned short)yv[4]) + x1.x; v[5] = bf2f((unsigned short)yv[5]) + x1.y;
        v[6] = bf2f((unsigned short)yv[6]) + x1.z; v[7] = bf2f((unsigned short)yv[7]) + x1.w;
    } else {
        const unsigned short* xp = xb + row * H + lane * 8;
        short8 xv = *reinterpret_cast<const short8*>(xp);
#pragma unroll
        for (int i = 0; i < 8; i++)
            v[i] = bf2f((unsigned short)yv[i]) + bf2f((unsigned short)xv[i]);
    }
    float s = 0.f, s2 = 0.f;
#pragma unroll
    for (int i = 0; i < 8; i++) { s += v[i]; s2 = fmaf(v[i], v[i], s2); }
#pragma unroll
    for (int off = 32; off; off >>= 1) {
        s += __shfl_xor(s, off);
        s2 += __shfl_xor(s2, off);
    }
    float mu = s * (1.0f / H);
    float var = s2 * (1.0f / H) - mu * mu;
    float inv = rsqrtf(var + 1e-5f);
    const float* gl = gamma + layer * H + lane * 8;
    const float* bl = beta + layer * H + lane * 8;
    float o[8];
#pragma unroll
    for (int i = 0; i < 8; i++)
        o[i] = (v[i] - mu) * inv * gl[i] + bl[i];
    if (out_f32) {
        float* op = of + row * H + lane * 8;
        *(float4*)(op) = make_float4(o[0], o[1], o[2], o[3]);
        *(float4*)(op + 4) = make_float4(o[4], o[5], o[6], o[7]);
    } else {
        unsigned short* op = ob + row * H + lane * 8;
        uint2 p0 = pack4bf(o[0], o[1], o[2], o[3]);
        uint2 p1 = pack4bf(o[4], o[5], o[6], o[7]);
        *(uint2*)(op) = p0;
        *(uint2*)(op + 4) = p1;
    }
}

extern "C" void kernel_launch(void* const* d_in, const int* in_sizes, int n_in,
                              void* d_out, int out_size, void* d_ws, size_t ws_size,
                              hipStream_t stream) {
    const float* x          = (const float*)d_in[0];
    const float* log_dt     = (const float*)d_in[1];
    const float* A_imag     = (const float*)d_in[2];
    const float* log_A_real = (const float*)d_in[3];
    const float* C          = (const float*)d_in[4];
    const float* D          = (const float*)d_in[5];
    const float* W          = (const float*)d_in[6];
    const float* bias       = (const float*)d_in[7];
    const float* gamma      = (const float*)d_in[8];
    const float* beta       = (const float*)d_in[9];

    char* ws = (char*)d_ws;
    unsigned short* xR   = (unsigned short*)(ws + 0);           // bf16 residual stream
    unsigned short* Sloc = (unsigned short*)(ws + 67108864);
    unsigned short* u_t  = (unsigned short*)(ws + 100663296);
    unsigned short* ybf  = (unsigned short*)(ws + 100663296);   // overlay: after conv, u_t dead
    unsigned short* y_t  = (unsigned short*)(ws + 134217728);
    unsigned short* yo   = (unsigned short*)(ws + 134217728);   // overlay: after transpose2, y_t dead
    unsigned short* Wbf  = (unsigned short*)(ws + 167772160);
    unsigned short* WV   = (unsigned short*)(ws + 171966464);   // Wstate then V per layer
    unsigned short* kmat = (unsigned short*)(ws + 176160768);
    float*          dA   = (float*)(ws + 176422912);
    float*          Ct   = (float*)(ws + 176947200);
    float* xout_final    = (float*)d_out;

    wconv_kernel<<<NL * 2 * H * H / 256, 256, 0, stream>>>(W, Wbf);
    params_kernel<<<NL * N2 * H / 256, 256, 0, stream>>>(log_dt, A_imag, log_A_real, C, dA, Ct);
    kergen_k_kernel<<<NL * H * 64 / 256, 256, 0, stream>>>(dA, Ct, kmat);

    for (int layer = 0; layer < NL; ++layer) {
        if (layer == 0)
            t1_f32_kernel<<<4096, 256, 0, stream>>>(x, u_t);
        // layers >=1: u_t was already produced (transposed) by ln_t of the previous layer
        kergenW_kernel<<<H * 64 * 64 / 256, 256, 0, stream>>>(dA, WV, layer);
        states_kernel<<<H, 256, 0, stream>>>(u_t, WV, Sloc);
        combine_kernel<<<H * Bsz * N2 / 256, 256, 0, stream>>>(Sloc, dA, layer);
        kergenV_kernel<<<H * 64 * 64 / 256, 256, 0, stream>>>(dA, Ct, WV, layer);
        conv_kernel<<<dim3(H, 2), 256, 0, stream>>>(u_t, kmat, WV, Sloc, D, y_t, layer);
        transpose2_kernel<<<4096, 256, 0, stream>>>(y_t, ybf);
        gemm_glu_kernel<<<dim3(BT / 128, H / 64), 256, 0, stream>>>(ybf, Wbf, bias, yo, layer);
        if (layer < NL - 1) {
            ln_t_kernel<<<BT / 64, 256, 0, stream>>>(yo, x, xR, gamma, beta,
                                                     xR, u_t, (layer == 0) ? 1 : 0, layer);
        } else {
            ln_kernel<<<BT / 4, 256, 0, stream>>>(yo, x, xR, gamma, beta,
                                                  xout_final, xR, 0, 1, layer);
        }
    }
}

// Round 6
// 841.316 us; speedup vs baseline: 1.1360x; 1.0154x over previous
//
#include <hip/hip_runtime.h>
#include <hip/hip_bf16.h>
#include <math.h>

#define H 512
#define NL 4
#define N2 32
#define Bsz 8
#define Lseq 4096
#define BT (Bsz*Lseq)        // 32768 total positions
#define LC2 64               // chunk length
#define NCC (BT/LC2)         // 512 chunks total
#define CPB (Lseq/LC2)       // 64 chunks per batch element

typedef __attribute__((ext_vector_type(8))) short short8;   // 8 bf16
typedef __attribute__((ext_vector_type(4))) float float4v;

// ---------------- ws layout (bytes) ----------------
// 0         : xR   (bf16 BT*H residual)        33554432
// 67108864  : Vbuf (bf16 H*64*64, V)            4194304   (freed Sloc slot)
// 100663296 : u_t  (bf16 H*BT) / ybf overlay   33554432
// 134217728 : y_t  (bf16 H*BT) / yo overlay    33554432
// 167772160 : Wbf  (bf16 NL*2H*H)               4194304
// 171966464 : Wst  (bf16 H*64*64, Wstate)       4194304
// 176160768 : kmat (bf16 NL*H*64)                262144
// 176422912 : dA   (fp32 NL*N2*2*H)              524288
// 176947200 : Ct   (fp32 NL*N2*2*H)              524288

__device__ __forceinline__ float bf2f(unsigned short u) {
    union { unsigned int i; float f; } x; x.i = ((unsigned int)u) << 16; return x.f;
}
__device__ __forceinline__ unsigned short f2bf(float f) {
    union { float f; unsigned int i; } x; x.f = f;
    unsigned int u = x.i + 0x7fff + ((x.i >> 16) & 1);
    return (unsigned short)(u >> 16);
}
__device__ __forceinline__ uint2 pack4bf(float a, float b, float c, float d) {
    uint2 r;
    r.x = (unsigned)f2bf(a) | ((unsigned)f2bf(b) << 16);
    r.y = (unsigned)f2bf(c) | ((unsigned)f2bf(d) << 16);
    return r;
}
__device__ __forceinline__ void async_copy16(const void* g, void* l) {
    __builtin_amdgcn_global_load_lds(
        (const __attribute__((address_space(1))) void*)g,
        (__attribute__((address_space(3))) void*)l, 16, 0, 0);
}

// ---------- convert W to bf16 ----------
__global__ void wconv_kernel(const float* __restrict__ W, unsigned short* __restrict__ Wbf) {
    int tid = blockIdx.x * 256 + threadIdx.x;
    Wbf[tid] = f2bf(W[tid]);
}

// ---------- per-(layer,n,h): dA = log(lambda), Ct = 2C(lambda-1)/A ----------
__global__ void params_kernel(const float* __restrict__ log_dt, const float* __restrict__ A_imag,
                              const float* __restrict__ log_A_real, const float* __restrict__ Cin,
                              float* __restrict__ dA, float* __restrict__ Ct) {
    int tid = blockIdx.x * 256 + threadIdx.x;   // ((layer*N2+n)*H + h)
    int h = tid % H;
    int n = (tid / H) % N2;
    int layer = tid / (H * N2);
    float dt = expf(log_dt[layer * H + h]);
    int pidx = (layer * H + h) * N2 + n;
    float Are = -expf(log_A_real[pidx]);
    float Aim = A_imag[pidx];
    float dre = Are * dt, dim = Aim * dt;
    float er = expf(dre);
    float lre = er * cosf(dim), lim = er * sinf(dim);
    float nre = lre - 1.0f, nim = lim;
    float inv = 1.0f / (Are * Are + Aim * Aim);
    float tre = (nre * Are + nim * Aim) * inv;
    float tim = (nim * Are - nre * Aim) * inv;
    float Ccre = Cin[pidx * 2], Ccim = Cin[pidx * 2 + 1];
    int oidx = ((layer * N2 + n) * 2) * H + h;
    dA[oidx] = dre;  dA[oidx + H] = dim;
    Ct[oidx] = 2.0f * (Ccre * tre - Ccim * tim);
    Ct[oidx + H] = 2.0f * (Ccre * tim + Ccim * tre);
}

// ---------- kernels k[d] = Re sum_n Ct_n lambda_n^d, all layers ----------
__global__ void kergen_k_kernel(const float* __restrict__ dA, const float* __restrict__ Ct,
                                unsigned short* __restrict__ kmat) {
    int t = blockIdx.x * 256 + threadIdx.x;     // (layer*H + h)*64 + d
    int d = t & 63;
    int h = (t >> 6) & (H - 1);
    int layer = t >> 15;
    float fd = (float)d;
    float sum = 0.f;
    for (int n = 0; n < N2; n++) {
        int base = ((layer * N2 + n) * 2) * H + h;
        float dre = dA[base], dim = dA[base + H];
        float Ctr = Ct[base], Cti = Ct[base + H];
        float e = expf(dre * fd);
        sum += Ctr * e * cosf(dim * fd) - Cti * e * sinf(dim * fd);
    }
    kmat[t] = f2bf(sum);
}

// ---------- Wstate[h][r][j]: r=2n -> Re(l^(63-j)), r=2n+1 -> Im ----------
__global__ void kergenW_kernel(const float* __restrict__ dA, unsigned short* __restrict__ Wst, int layer) {
    int t = blockIdx.x * 256 + threadIdx.x;     // (h*64 + r)*64 + j
    int j = t & 63;
    int r = (t >> 6) & 63;
    int h = t >> 12;
    int n = r >> 1;
    int base = ((layer * N2 + n) * 2) * H + h;
    float dre = dA[base], dim = dA[base + H];
    float p = (float)(63 - j);
    float e = expf(dre * p);
    Wst[t] = f2bf((r & 1) ? e * sinf(dim * p) : e * cosf(dim * p));
}

// ---------- V[h][l][c2]: c2=2n -> Re(Ct l^(l+1)), c2=2n+1 -> -Im ----------
__global__ void kergenV_kernel(const float* __restrict__ dA, const float* __restrict__ Ct,
                               unsigned short* __restrict__ Vl, int layer) {
    int t = blockIdx.x * 256 + threadIdx.x;     // (h*64 + l)*64 + c2
    int c2 = t & 63;
    int l = (t >> 6) & 63;
    int h = t >> 12;
    int n = c2 >> 1;
    int base = ((layer * N2 + n) * 2) * H + h;
    float dre = dA[base], dim = dA[base + H];
    float Ctr = Ct[base], Cti = Ct[base + H];
    float q = (float)(l + 1);
    float e = expf(dre * q);
    float ar = e * cosf(dim * q), ai = e * sinf(dim * q);
    float vre = Ctr * ar - Cti * ai;
    float vim = Ctr * ai + Cti * ar;
    Vl[t] = f2bf((c2 & 1) ? -vim : vre);
}

// ---------- transpose x fp32 (BT,H) -> u_t bf16 (H,BT)  [layer 0 only] ----------
__global__ __launch_bounds__(256) void t1_f32_kernel(const float* __restrict__ xi,
                                                     unsigned short* __restrict__ ut) {
    __shared__ float tile[64][68];
    int bx = blockIdx.x;
    int pt = bx & 511, ht = bx >> 9;
    int p0 = pt * 64, h0 = ht * 64;
    int t = threadIdx.x;
    int jr = t & 15, ib = t >> 4;
#pragma unroll
    for (int pass = 0; pass < 4; pass++) {
        int i = ib + pass * 16;
        float4 v = *(const float4*)(xi + (size_t)(p0 + i) * H + h0 + jr * 4);
        *(float4*)(&tile[i][jr * 4]) = v;   // 272B row stride -> 16B aligned
    }
    __syncthreads();
#pragma unroll
    for (int pass = 0; pass < 4; pass++) {
        int i2 = ib + pass * 16;
        int j2 = jr * 4;
        uint2 pk = pack4bf(tile[j2][i2], tile[j2 + 1][i2], tile[j2 + 2][i2], tile[j2 + 3][i2]);
        *(uint2*)(ut + (size_t)(h0 + i2) * BT + p0 + j2) = pk;
    }
}

// ---------- FUSED SSM: local states + chunk-scan + Toeplitz/state conv + gelu ----------
// One block per (h, batch). Eliminates Sloc (128MB/layer) and extra u_t reads.
// Phase 1 = old states_kernel MFMA; phase 2 = old combine_kernel scan (wave 0,
// lane-per-r, shfl_xor complex update); phase 3 = old conv_kernel GEMMs + epilogue.
__global__ __launch_bounds__(256) void ssm_kernel(const unsigned short* __restrict__ ut,
                                                  const unsigned short* __restrict__ kmat,
                                                  const unsigned short* __restrict__ Wst,
                                                  const unsigned short* __restrict__ Vl,
                                                  const float* __restrict__ dA,
                                                  const float* __restrict__ Dp,
                                                  unsigned short* __restrict__ yt, int layer) {
    __shared__ unsigned short T[64][72];    // Toeplitz
    __shared__ unsigned short Sl[64][72];   // local chunk states (bf16)
    __shared__ unsigned short El[64][72];   // entering chunk states (bf16)
    int h = blockIdx.x, b = blockIdx.y;
    int t = threadIdx.x;
    const unsigned short* km = kmat + ((size_t)layer * H + h) * 64;
    {   // build lower-triangular Toeplitz T[l][j] = k[l-j]
        int l = t >> 2, j0 = (t & 3) * 16;
#pragma unroll
        for (int g = 0; g < 2; g++) {
            short8 v;
#pragma unroll
            for (int e = 0; e < 8; e++) {
                int j = j0 + g * 8 + e;
                v[e] = (j <= l) ? (short)km[l - j] : (short)0;
            }
            *reinterpret_cast<short8*>(&T[l][j0 + g * 8]) = v;
        }
    }
    int wave = t >> 6, lane = t & 63;
    int r16 = lane & 15, quad = lane >> 4;
    const unsigned short* uh = ut + (size_t)h * BT + (size_t)b * Lseq;   // 4096 positions
    const unsigned short* wh = Wst + (size_t)h * 64 * 64;
    const unsigned short* vh = Vl + (size_t)h * 64 * 64;

    // ---- phase 1: local states Sl[cc][r] = sum_j Wst[r][j] u[cc*64+j] ----
    {
        int cc0 = wave * 16;
        float4v acc[4] = {};
#pragma unroll
        for (int k0 = 0; k0 < 64; k0 += 32) {
            short8 bf = *reinterpret_cast<const short8*>(uh + (size_t)(cc0 + r16) * 64 + k0 + quad * 8);
#pragma unroll
            for (int mt = 0; mt < 4; mt++) {
                short8 af = *reinterpret_cast<const short8*>(wh + (mt * 16 + r16) * 64 + k0 + quad * 8);
                acc[mt] = __builtin_amdgcn_mfma_f32_16x16x32_bf16(af, bf, acc[mt], 0, 0, 0);
            }
        }
        int cc = cc0 + r16;
#pragma unroll
        for (int mt = 0; mt < 4; mt++) {
            uint2 pk = pack4bf(acc[mt][0], acc[mt][1], acc[mt][2], acc[mt][3]);
            *(uint2*)(&Sl[cc][mt * 16 + quad * 4]) = pk;
        }
    }
    __syncthreads();

    // ---- phase 2: serial scan over 64 chunks (wave 0; lane = r; partner via shfl) ----
    if (wave == 0) {
        int r = lane;
        int n = r >> 1;
        int base = ((layer * N2 + n) * 2) * H + h;
        float dre = dA[base], dim = dA[base + H];
        float e = expf(dre * 64.f);
        float Lr = e * cosf(dim * 64.f), Li = e * sinf(dim * 64.f);
        float Ls = (r & 1) ? Li : -Li;     // even(re): -Li*im ; odd(im): +Li*re
        float s = 0.f;
        for (int c = 0; c < 64; c++) {
            El[c][r] = f2bf(s);
            float p = bf2f(Sl[c][r]);
            float sp = __shfl_xor(s, 1);
            s = fmaf(Lr, s, fmaf(Ls, sp, p));
        }
    }
    __syncthreads();

    // ---- phase 3: y = T*u + V*E, + D*u, gelu ----
    {
        int cc0 = wave * 16;
        float4v acc[4] = {};
#pragma unroll
        for (int k0 = 0; k0 < 64; k0 += 32) {    // Toeplitz part (u from global, L1-hot)
            short8 bf = *reinterpret_cast<const short8*>(uh + (size_t)(cc0 + r16) * 64 + k0 + quad * 8);
#pragma unroll
            for (int mt = 0; mt < 4; mt++) {
                short8 af = *reinterpret_cast<const short8*>(&T[mt * 16 + r16][k0 + quad * 8]);
                acc[mt] = __builtin_amdgcn_mfma_f32_16x16x32_bf16(af, bf, acc[mt], 0, 0, 0);
            }
        }
#pragma unroll
        for (int k0 = 0; k0 < 64; k0 += 32) {    // entering-state correction (E from LDS)
            short8 bf = *reinterpret_cast<const short8*>(&El[cc0 + r16][k0 + quad * 8]);
#pragma unroll
            for (int mt = 0; mt < 4; mt++) {
                short8 af = *reinterpret_cast<const short8*>(vh + (mt * 16 + r16) * 64 + k0 + quad * 8);
                acc[mt] = __builtin_amdgcn_mfma_f32_16x16x32_bf16(af, bf, acc[mt], 0, 0, 0);
            }
        }
        float Dh = Dp[layer * H + h];
        int cc = cc0 + r16;
        unsigned short* yh = yt + (size_t)h * BT + (size_t)b * Lseq;
#pragma unroll
        for (int mt = 0; mt < 4; mt++) {
            size_t p = (size_t)cc * 64 + mt * 16 + quad * 4;
            ushort4 uu = *(const ushort4*)(uh + p);
            float o[4];
#pragma unroll
            for (int r = 0; r < 4; r++) {
                float y = acc[mt][r] + Dh * bf2f(((const unsigned short*)&uu)[r]);
                o[r] = 0.5f * y * (1.0f + erff(y * 0.70710678118654752f));
            }
            *(uint2*)(yh + p) = pack4bf(o[0], o[1], o[2], o[3]);
        }
    }
}

// ---------- transpose y_t (H,BT bf16) -> ybf (BT,H bf16) ----------
__global__ __launch_bounds__(256) void transpose2_kernel(const unsigned short* __restrict__ yt,
                                                         unsigned short* __restrict__ yb) {
    __shared__ unsigned short tile[64][72];
    int bx = blockIdx.x;
    int pt = bx & 511, ht = bx >> 9;
    int p0 = pt * 64, h0 = ht * 64;
    int t = threadIdx.x;
    int jr = t & 7, ib = t >> 3;
#pragma unroll
    for (int pass = 0; pass < 2; pass++) {
        int i = ib + pass * 32;
        short8 v = *reinterpret_cast<const short8*>(yt + (size_t)(h0 + i) * BT + p0 + jr * 8);
        *reinterpret_cast<short8*>(&tile[i][jr * 8]) = v;   // 144B row stride -> 16B aligned
    }
    __syncthreads();
    int pp = t >> 2, hg = t & 3;
    short8 o0, o1;
#pragma unroll
    for (int r = 0; r < 8; r++) o0[r] = (short)tile[hg * 16 + r][pp];
#pragma unroll
    for (int r = 0; r < 8; r++) o1[r] = (short)tile[hg * 16 + 8 + r][pp];
    unsigned short* dst = yb + (size_t)(p0 + pp) * H + h0 + hg * 16;
    *reinterpret_cast<short8*>(dst) = o0;
    *reinterpret_cast<short8*>(dst + 8) = o1;
}

// ---------- fused 1x1 conv (LDS-tiled, bank-conflict-free swizzle) + bias + GLU ----------
// v2 (proven): triple-buffered LDS, depth-2 prefetch, raw s_barrier + counted vmcnt.
// LDS chunk (row r, c) holds global chunk (r, c ^ ((r>>1)&3)); reads use the inverse.
__global__ __launch_bounds__(256) void gemm_glu_kernel(const unsigned short* __restrict__ ybf,
                                                       const unsigned short* __restrict__ Wbf,
                                                       const float* __restrict__ bias,
                                                       unsigned short* __restrict__ yo, int layer) {
    __shared__ unsigned short As[3][128 * 32];
    __shared__ unsigned short Bs[3][128 * 32];
    int tid = threadIdx.x;
    int wave = tid >> 6, lane = tid & 63;
    int wr = wave >> 1, wc = wave & 1;
    int r16 = lane & 15, quad = lane >> 4;
    int m0 = blockIdx.x * 128;
    int o0 = blockIdx.y * 64;
    const unsigned short* Wl = Wbf + (size_t)layer * 2 * H * H;

    // staging: lane -> LDS row lane>>2, chunk lane&3; source col chunk is XOR-swizzled
    int srow = lane >> 2;
    int scol = ((lane & 3) ^ ((srow >> 1) & 3)) * 8;
    const unsigned short* aS0 = ybf + ((size_t)(m0 + wave * 16 + srow)) * H + scol;
    const unsigned short* aS1 = aS0 + (size_t)64 * H;
    const unsigned short* bSA = Wl + ((size_t)(o0 + wave * 16 + srow)) * H + scol;
    const unsigned short* bSG = bSA + (size_t)512 * H;
    const int aoff0 = (wave * 16) * 32;          // wave-uniform LDS dest offsets
    const int aoff1 = (64 + wave * 16) * 32;

    int rcol = (quad ^ ((r16 >> 1) & 3)) * 8;   // swizzled fragment column

    float4v acc_a[4][2] = {}, acc_g[4][2] = {};

    // ---- prologue: prefetch K-steps 0 and 1 into buffers 0 and 1 ----
    async_copy16(aS0,      &As[0][aoff0]);
    async_copy16(aS1,      &As[0][aoff1]);
    async_copy16(bSA,      &Bs[0][aoff0]);
    async_copy16(bSG,      &Bs[0][aoff1]);
    async_copy16(aS0 + 32, &As[1][aoff0]);
    async_copy16(aS1 + 32, &As[1][aoff1]);
    async_copy16(bSA + 32, &Bs[1][aoff0]);
    async_copy16(bSG + 32, &Bs[1][aoff1]);
    asm volatile("s_waitcnt vmcnt(4)" ::: "memory");   // buffer 0 landed
    __builtin_amdgcn_s_barrier();

#pragma unroll
    for (int ks = 0; ks < 16; ++ks) {
        const int b = ks % 3;
        if (ks < 14) {   // issue depth-2 prefetch BEFORE compute; overwrites buf read at ks-1
            const int nb = (ks + 2) % 3;
            const int kn = (ks + 2) * 32;
            async_copy16(aS0 + kn, &As[nb][aoff0]);
            async_copy16(aS1 + kn, &As[nb][aoff1]);
            async_copy16(bSA + kn, &Bs[nb][aoff0]);
            async_copy16(bSG + kn, &Bs[nb][aoff1]);
        }

        short8 af[4], ba[2], bg[2];
#pragma unroll
        for (int mi = 0; mi < 4; mi++)
            af[mi] = *reinterpret_cast<const short8*>(&As[b][(wr * 64 + mi * 16 + r16) * 32 + rcol]);
#pragma unroll
        for (int ni = 0; ni < 2; ni++) {
            ba[ni] = *reinterpret_cast<const short8*>(&Bs[b][(wc * 32 + ni * 16 + r16) * 32 + rcol]);
            bg[ni] = *reinterpret_cast<const short8*>(&Bs[b][(64 + wc * 32 + ni * 16 + r16) * 32 + rcol]);
        }
#pragma unroll
        for (int mi = 0; mi < 4; mi++)
#pragma unroll
            for (int ni = 0; ni < 2; ni++) {
                acc_a[mi][ni] = __builtin_amdgcn_mfma_f32_16x16x32_bf16(af[mi], ba[ni], acc_a[mi][ni], 0, 0, 0);
                acc_g[mi][ni] = __builtin_amdgcn_mfma_f32_16x16x32_bf16(af[mi], bg[ni], acc_g[mi][ni], 0, 0, 0);
            }

        // boundary: all my LDS reads done; oldest prefetch (next buffer) landed; all waves synced.
        if (ks < 14) {
            asm volatile("s_waitcnt vmcnt(4) lgkmcnt(0)" ::: "memory");
            __builtin_amdgcn_s_barrier();
        } else if (ks == 14) {
            asm volatile("s_waitcnt vmcnt(0) lgkmcnt(0)" ::: "memory");
            __builtin_amdgcn_s_barrier();
        }
    }

    const float* bl = bias + layer * 2 * H;
#pragma unroll
    for (int ni = 0; ni < 2; ni++) {
        int o = o0 + wc * 32 + ni * 16 + r16;
        float ba_ = bl[o], bg_ = bl[H + o];
#pragma unroll
        for (int mi = 0; mi < 4; mi++)
#pragma unroll
            for (int r = 0; r < 4; r++) {
                int l = m0 + wr * 64 + mi * 16 + quad * 4 + r;
                float av = acc_a[mi][ni][r] + ba_;
                float gv = acc_g[mi][ni][r] + bg_;
                yo[(size_t)l * H + o] = f2bf(av * (1.0f / (1.0f + expf(-gv))));
            }
    }
}

// ---------- fused residual + LayerNorm + transpose-out (layers 0..2) ----------
__global__ __launch_bounds__(256) void ln_t_kernel(const unsigned short* __restrict__ yo,
                                                   const float* __restrict__ xf,
                                                   const unsigned short* __restrict__ xb,
                                                   const float* __restrict__ gamma,
                                                   const float* __restrict__ beta,
                                                   unsigned short* __restrict__ xR,
                                                   unsigned short* __restrict__ ut,
                                                   int in_f32, int layer) {
    __shared__ unsigned short tl[64][520];   // [p-local][h]; 1040B row stride (16B aligned)
    int t = threadIdx.x;
    int p0 = blockIdx.x * 64;
    int lane8 = t & 7;          // 8 lanes share one row
    int rowb = t >> 3;          // 0..31
    const float* gl = gamma + layer * H;
    const float* bl = beta + layer * H;
#pragma unroll
    for (int rr = 0; rr < 2; rr++) {
        int row = rowb + rr * 32;
        size_t gbase = (size_t)(p0 + row) * H;
        float v[64];
        float s = 0.f, s2 = 0.f;
#pragma unroll
        for (int cc = 0; cc < 8; cc++) {
            int h0 = (lane8 + cc * 8) * 8;
            short8 yv = *reinterpret_cast<const short8*>(yo + gbase + h0);
            if (in_f32) {
                float4 x0 = *(const float4*)(xf + gbase + h0);
                float4 x1 = *(const float4*)(xf + gbase + h0 + 4);
                v[cc * 8 + 0] = bf2f((unsigned short)yv[0]) + x0.x;
                v[cc * 8 + 1] = bf2f((unsigned short)yv[1]) + x0.y;
                v[cc * 8 + 2] = bf2f((unsigned short)yv[2]) + x0.z;
                v[cc * 8 + 3] = bf2f((unsigned short)yv[3]) + x0.w;
                v[cc * 8 + 4] = bf2f((unsigned short)yv[4]) + x1.x;
                v[cc * 8 + 5] = bf2f((unsigned short)yv[5]) + x1.y;
                v[cc * 8 + 6] = bf2f((unsigned short)yv[6]) + x1.z;
                v[cc * 8 + 7] = bf2f((unsigned short)yv[7]) + x1.w;
            } else {
                short8 xv = *reinterpret_cast<const short8*>(xb + gbase + h0);
#pragma unroll
                for (int i = 0; i < 8; i++)
                    v[cc * 8 + i] = bf2f((unsigned short)yv[i]) + bf2f((unsigned short)xv[i]);
            }
#pragma unroll
            for (int i = 0; i < 8; i++) { s += v[cc * 8 + i]; s2 = fmaf(v[cc * 8 + i], v[cc * 8 + i], s2); }
        }
        s += __shfl_xor(s, 1);  s2 += __shfl_xor(s2, 1);
        s += __shfl_xor(s, 2);  s2 += __shfl_xor(s2, 2);
        s += __shfl_xor(s, 4);  s2 += __shfl_xor(s2, 4);
        float mu = s * (1.0f / H);
        float var = s2 * (1.0f / H) - mu * mu;
        float inv = rsqrtf(var + 1e-5f);
#pragma unroll
        for (int cc = 0; cc < 8; cc++) {
            int h0 = (lane8 + cc * 8) * 8;
            float4 g0 = *(const float4*)(gl + h0);
            float4 g1 = *(const float4*)(gl + h0 + 4);
            float4 b0 = *(const float4*)(bl + h0);
            float4 b1 = *(const float4*)(bl + h0 + 4);
            short8 pk;
            pk[0] = (short)f2bf((v[cc * 8 + 0] - mu) * inv * g0.x + b0.x);
            pk[1] = (short)f2bf((v[cc * 8 + 1] - mu) * inv * g0.y + b0.y);
            pk[2] = (short)f2bf((v[cc * 8 + 2] - mu) * inv * g0.z + b0.z);
            pk[3] = (short)f2bf((v[cc * 8 + 3] - mu) * inv * g0.w + b0.w);
            pk[4] = (short)f2bf((v[cc * 8 + 4] - mu) * inv * g1.x + b1.x);
            pk[5] = (short)f2bf((v[cc * 8 + 5] - mu) * inv * g1.y + b1.y);
            pk[6] = (short)f2bf((v[cc * 8 + 6] - mu) * inv * g1.z + b1.z);
            pk[7] = (short)f2bf((v[cc * 8 + 7] - mu) * inv * g1.w + b1.w);
            *reinterpret_cast<short8*>(xR + gbase + h0) = pk;
            *reinterpret_cast<short8*>(&tl[row][h0]) = pk;
        }
    }
    __syncthreads();
#pragma unroll
    for (int hh = 0; hh < 2; hh++) {
        int h = t + hh * 256;
        unsigned short* dst = ut + (size_t)h * BT + p0;
#pragma unroll
        for (int pc = 0; pc < 8; pc++) {
            short8 o;
#pragma unroll
            for (int e = 0; e < 8; e++) o[e] = (short)tl[pc * 8 + e][h];
            *reinterpret_cast<short8*>(dst + pc * 8) = o;
        }
    }
}

// ---------- residual + LayerNorm (final layer: fp32 out) ----------
__global__ __launch_bounds__(256) void ln_kernel(const unsigned short* __restrict__ yo,
                                                 const float* __restrict__ xf,
                                                 const unsigned short* __restrict__ xb,
                                                 const float* __restrict__ gamma, const float* __restrict__ beta,
                                                 float* __restrict__ of, unsigned short* __restrict__ ob,
                                                 int in_f32, int out_f32, int layer) {
    int wave = threadIdx.x >> 6, lane = threadIdx.x & 63;
    size_t row = (size_t)blockIdx.x * 4 + wave;
    const unsigned short* yp = yo + row * H + lane * 8;
    short8 yv = *reinterpret_cast<const short8*>(yp);
    float v[8];
    if (in_f32) {
        const float* xp = xf + row * H + lane * 8;
        float4 x0 = *(const float4*)(xp);
        float4 x1 = *(const float4*)(xp + 4);
        v[0] = bf2f((unsigned short)yv[0]) + x0.x; v[1] = bf2f((unsigned short)yv[1]) + x0.y;
        v[2] = bf2f((unsigned short)yv[2]) + x0.z; v[3] = bf2f((unsigned short)yv[3]) + x0.w;
        v[4] = bf2f((unsigned short)yv[4]) + x1.x; v[5] = bf2f((unsigned short)yv[5]) + x1.y;
        v[6] = bf2f((unsigned short)yv[6]) + x1.z; v[7] = bf2f((unsigned short)yv[7]) + x1.w;
    } else {
        const unsigned short* xp = xb + row * H + lane * 8;
        short8 xv = *reinterpret_cast<const short8*>(xp);
#pragma unroll
        for (int i = 0; i < 8; i++)
            v[i] = bf2f((unsigned short)yv[i]) + bf2f((unsigned short)xv[i]);
    }
    float s = 0.f, s2 = 0.f;
#pragma unroll
    for (int i = 0; i < 8; i++) { s += v[i]; s2 = fmaf(v[i], v[i], s2); }
#pragma unroll
    for (int off = 32; off; off >>= 1) {
        s += __shfl_xor(s, off);
        s2 += __shfl_xor(s2, off);
    }
    float mu = s * (1.0f / H);
    float var = s2 * (1.0f / H) - mu * mu;
    float inv = rsqrtf(var + 1e-5f);
    const float* gl = gamma + layer * H + lane * 8;
    const float* bl = beta + layer * H + lane * 8;
    float o[8];
#pragma unroll
    for (int i = 0; i < 8; i++)
        o[i] = (v[i] - mu) * inv * gl[i] + bl[i];
    if (out_f32) {
        float* op = of + row * H + lane * 8;
        *(float4*)(op) = make_float4(o[0], o[1], o[2], o[3]);
        *(float4*)(op + 4) = make_float4(o[4], o[5], o[6], o[7]);
    } else {
        unsigned short* op = ob + row * H + lane * 8;
        uint2 p0 = pack4bf(o[0], o[1], o[2], o[3]);
        uint2 p1 = pack4bf(o[4], o[5], o[6], o[7]);
        *(uint2*)(op) = p0;
        *(uint2*)(op + 4) = p1;
    }
}

extern "C" void kernel_launch(void* const* d_in, const int* in_sizes, int n_in,
                              void* d_out, int out_size, void* d_ws, size_t ws_size,
                              hipStream_t stream) {
    const float* x          = (const float*)d_in[0];
    const float* log_dt     = (const float*)d_in[1];
    const float* A_imag     = (const float*)d_in[2];
    const float* log_A_real = (const float*)d_in[3];
    const float* C          = (const float*)d_in[4];
    const float* D          = (const float*)d_in[5];
    const float* W          = (const float*)d_in[6];
    const float* bias       = (const float*)d_in[7];
    const float* gamma      = (const float*)d_in[8];
    const float* beta       = (const float*)d_in[9];

    char* ws = (char*)d_ws;
    unsigned short* xR   = (unsigned short*)(ws + 0);           // bf16 residual stream
    unsigned short* Vbuf = (unsigned short*)(ws + 67108864);    // V (freed Sloc slot)
    unsigned short* u_t  = (unsigned short*)(ws + 100663296);
    unsigned short* ybf  = (unsigned short*)(ws + 100663296);   // overlay: after ssm, u_t dead
    unsigned short* y_t  = (unsigned short*)(ws + 134217728);
    unsigned short* yo   = (unsigned short*)(ws + 134217728);   // overlay: after transpose2, y_t dead
    unsigned short* Wbf  = (unsigned short*)(ws + 167772160);
    unsigned short* Wstb = (unsigned short*)(ws + 171966464);   // Wstate
    unsigned short* kmat = (unsigned short*)(ws + 176160768);
    float*          dA   = (float*)(ws + 176422912);
    float*          Ct   = (float*)(ws + 176947200);
    float* xout_final    = (float*)d_out;

    wconv_kernel<<<NL * 2 * H * H / 256, 256, 0, stream>>>(W, Wbf);
    params_kernel<<<NL * N2 * H / 256, 256, 0, stream>>>(log_dt, A_imag, log_A_real, C, dA, Ct);
    kergen_k_kernel<<<NL * H * 64 / 256, 256, 0, stream>>>(dA, Ct, kmat);

    for (int layer = 0; layer < NL; ++layer) {
        if (layer == 0)
            t1_f32_kernel<<<4096, 256, 0, stream>>>(x, u_t);
        // layers >=1: u_t was already produced (transposed) by ln_t of the previous layer
        kergenW_kernel<<<H * 64 * 64 / 256, 256, 0, stream>>>(dA, Wstb, layer);
        kergenV_kernel<<<H * 64 * 64 / 256, 256, 0, stream>>>(dA, Ct, Vbuf, layer);
        ssm_kernel<<<dim3(H, Bsz), 256, 0, stream>>>(u_t, kmat, Wstb, Vbuf, dA, D, y_t, layer);
        transpose2_kernel<<<4096, 256, 0, stream>>>(y_t, ybf);
        gemm_glu_kernel<<<dim3(BT / 128, H / 64), 256, 0, stream>>>(ybf, Wbf, bias, yo, layer);
        if (layer < NL - 1) {
            ln_t_kernel<<<BT / 64, 256, 0, stream>>>(yo, x, xR, gamma, beta,
                                                     xR, u_t, (layer == 0) ? 1 : 0, layer);
        } else {
            ln_kernel<<<BT / 4, 256, 0, stream>>>(yo, x, xR, gamma, beta,
                                                  xout_final, xR, 0, 1, layer);
        }
    }
}

// Round 7
// 838.199 us; speedup vs baseline: 1.1402x; 1.0037x over previous
//
#include <hip/hip_runtime.h>
#include <hip/hip_bf16.h>
#include <math.h>

#define H 512
#define NL 4
#define N2 32
#define Bsz 8
#define Lseq 4096
#define BT (Bsz*Lseq)        // 32768 total positions
#define LC2 64               // chunk length
#define NCC (BT/LC2)         // 512 chunks total
#define CPB (Lseq/LC2)       // 64 chunks per batch element

typedef __attribute__((ext_vector_type(8))) short short8;   // 8 bf16
typedef __attribute__((ext_vector_type(4))) float float4v;

// ---------------- ws layout (bytes) ----------------
// 0         : xR   (bf16 BT*H residual)        33554432
// 67108864  : Vbuf (bf16 H*64*64, V)            4194304
// 100663296 : u_t  (bf16 H*BT) / ybf overlay   33554432
// 134217728 : y_t  (bf16 H*BT) / yo overlay    33554432
// 167772160 : Wbf  (bf16 NL*2H*H)               4194304
// 171966464 : Wst  (bf16 H*64*64, Wstate)       4194304
// 176160768 : kmat (bf16 NL*H*64)                262144
// 176422912 : dA   (fp32 NL*N2*2*H)              524288
// 176947200 : Ct   (fp32 NL*N2*2*H)              524288

__device__ __forceinline__ float bf2f(unsigned short u) {
    union { unsigned int i; float f; } x; x.i = ((unsigned int)u) << 16; return x.f;
}
__device__ __forceinline__ unsigned short f2bf(float f) {
    union { float f; unsigned int i; } x; x.f = f;
    unsigned int u = x.i + 0x7fff + ((x.i >> 16) & 1);
    return (unsigned short)(u >> 16);
}
__device__ __forceinline__ uint2 pack4bf(float a, float b, float c, float d) {
    uint2 r;
    r.x = (unsigned)f2bf(a) | ((unsigned)f2bf(b) << 16);
    r.y = (unsigned)f2bf(c) | ((unsigned)f2bf(d) << 16);
    return r;
}
__device__ __forceinline__ void async_copy16(const void* g, void* l) {
    __builtin_amdgcn_global_load_lds(
        (const __attribute__((address_space(1))) void*)g,
        (__attribute__((address_space(3))) void*)l, 16, 0, 0);
}

// ---------- convert W to bf16 ----------
__global__ void wconv_kernel(const float* __restrict__ W, unsigned short* __restrict__ Wbf) {
    int tid = blockIdx.x * 256 + threadIdx.x;
    Wbf[tid] = f2bf(W[tid]);
}

// ---------- per-(layer,n,h): dA = log(lambda), Ct = 2C(lambda-1)/A ----------
__global__ void params_kernel(const float* __restrict__ log_dt, const float* __restrict__ A_imag,
                              const float* __restrict__ log_A_real, const float* __restrict__ Cin,
                              float* __restrict__ dA, float* __restrict__ Ct) {
    int tid = blockIdx.x * 256 + threadIdx.x;   // ((layer*N2+n)*H + h)
    int h = tid % H;
    int n = (tid / H) % N2;
    int layer = tid / (H * N2);
    float dt = expf(log_dt[layer * H + h]);
    int pidx = (layer * H + h) * N2 + n;
    float Are = -expf(log_A_real[pidx]);
    float Aim = A_imag[pidx];
    float dre = Are * dt, dim = Aim * dt;
    float er = expf(dre);
    float lre = er * cosf(dim), lim = er * sinf(dim);
    float nre = lre - 1.0f, nim = lim;
    float inv = 1.0f / (Are * Are + Aim * Aim);
    float tre = (nre * Are + nim * Aim) * inv;
    float tim = (nim * Are - nre * Aim) * inv;
    float Ccre = Cin[pidx * 2], Ccim = Cin[pidx * 2 + 1];
    int oidx = ((layer * N2 + n) * 2) * H + h;
    dA[oidx] = dre;  dA[oidx + H] = dim;
    Ct[oidx] = 2.0f * (Ccre * tre - Ccim * tim);
    Ct[oidx + H] = 2.0f * (Ccre * tim + Ccim * tre);
}

// ---------- kernels k[d] = Re sum_n Ct_n lambda_n^d, all layers ----------
__global__ void kergen_k_kernel(const float* __restrict__ dA, const float* __restrict__ Ct,
                                unsigned short* __restrict__ kmat) {
    int t = blockIdx.x * 256 + threadIdx.x;     // (layer*H + h)*64 + d
    int d = t & 63;
    int h = (t >> 6) & (H - 1);
    int layer = t >> 15;
    float fd = (float)d;
    float sum = 0.f;
    for (int n = 0; n < N2; n++) {
        int base = ((layer * N2 + n) * 2) * H + h;
        float dre = dA[base], dim = dA[base + H];
        float Ctr = Ct[base], Cti = Ct[base + H];
        float e = expf(dre * fd);
        sum += Ctr * e * cosf(dim * fd) - Cti * e * sinf(dim * fd);
    }
    kmat[t] = f2bf(sum);
}

// ---------- Wstate[h][r][j]: r=2n -> Re(l^(63-j)), r=2n+1 -> Im ----------
__global__ void kergenW_kernel(const float* __restrict__ dA, unsigned short* __restrict__ Wst, int layer) {
    int t = blockIdx.x * 256 + threadIdx.x;     // (h*64 + r)*64 + j
    int j = t & 63;
    int r = (t >> 6) & 63;
    int h = t >> 12;
    int n = r >> 1;
    int base = ((layer * N2 + n) * 2) * H + h;
    float dre = dA[base], dim = dA[base + H];
    float p = (float)(63 - j);
    float e = expf(dre * p);
    Wst[t] = f2bf((r & 1) ? e * sinf(dim * p) : e * cosf(dim * p));
}

// ---------- V[h][l][c2]: c2=2n -> Re(Ct l^(l+1)), c2=2n+1 -> -Im ----------
__global__ void kergenV_kernel(const float* __restrict__ dA, const float* __restrict__ Ct,
                               unsigned short* __restrict__ Vl, int layer) {
    int t = blockIdx.x * 256 + threadIdx.x;     // (h*64 + l)*64 + c2
    int c2 = t & 63;
    int l = (t >> 6) & 63;
    int h = t >> 12;
    int n = c2 >> 1;
    int base = ((layer * N2 + n) * 2) * H + h;
    float dre = dA[base], dim = dA[base + H];
    float Ctr = Ct[base], Cti = Ct[base + H];
    float q = (float)(l + 1);
    float e = expf(dre * q);
    float ar = e * cosf(dim * q), ai = e * sinf(dim * q);
    float vre = Ctr * ar - Cti * ai;
    float vim = Ctr * ai + Cti * ar;
    Vl[t] = f2bf((c2 & 1) ? -vim : vre);
}

// ---------- transpose x fp32 (BT,H) -> u_t bf16 (H,BT)  [layer 0 only] ----------
__global__ __launch_bounds__(256) void t1_f32_kernel(const float* __restrict__ xi,
                                                     unsigned short* __restrict__ ut) {
    __shared__ float tile[64][68];
    int bx = blockIdx.x;
    int pt = bx & 511, ht = bx >> 9;
    int p0 = pt * 64, h0 = ht * 64;
    int t = threadIdx.x;
    int jr = t & 15, ib = t >> 4;
#pragma unroll
    for (int pass = 0; pass < 4; pass++) {
        int i = ib + pass * 16;
        float4 v = *(const float4*)(xi + (size_t)(p0 + i) * H + h0 + jr * 4);
        *(float4*)(&tile[i][jr * 4]) = v;   // 272B row stride -> 16B aligned
    }
    __syncthreads();
#pragma unroll
    for (int pass = 0; pass < 4; pass++) {
        int i2 = ib + pass * 16;
        int j2 = jr * 4;
        uint2 pk = pack4bf(tile[j2][i2], tile[j2 + 1][i2], tile[j2 + 2][i2], tile[j2 + 3][i2]);
        *(uint2*)(ut + (size_t)(h0 + i2) * BT + p0 + j2) = pk;
    }
}

// ---------- FUSED SSM v2: 4-wave segmented scan ----------
// One block per (h, batch). Phase 2 now: each wave scans its own 16 chunks
// (local E in fp32 regs), fp32 segment totals -> LDS, carry fixup, in-place
// write of entering states into Sl. Serial depth 64 -> ~16; all waves busy;
// El buffer eliminated (LDS 27.6 -> 19.4 KB => 8 blocks/CU).
__global__ __launch_bounds__(256) void ssm_kernel(const unsigned short* __restrict__ ut,
                                                  const unsigned short* __restrict__ kmat,
                                                  const unsigned short* __restrict__ Wst,
                                                  const unsigned short* __restrict__ Vl,
                                                  const float* __restrict__ dA,
                                                  const float* __restrict__ Dp,
                                                  unsigned short* __restrict__ yt, int layer) {
    __shared__ unsigned short T[64][72];    // Toeplitz
    __shared__ unsigned short Sl[64][72];   // local states -> (in place) entering states
    __shared__ float Tw[4][64];             // fp32 per-wave segment totals
    int h = blockIdx.x, b = blockIdx.y;
    int t = threadIdx.x;
    const unsigned short* km = kmat + ((size_t)layer * H + h) * 64;
    {   // build lower-triangular Toeplitz T[l][j] = k[l-j]
        int l = t >> 2, j0 = (t & 3) * 16;
#pragma unroll
        for (int g = 0; g < 2; g++) {
            short8 v;
#pragma unroll
            for (int e = 0; e < 8; e++) {
                int j = j0 + g * 8 + e;
                v[e] = (j <= l) ? (short)km[l - j] : (short)0;
            }
            *reinterpret_cast<short8*>(&T[l][j0 + g * 8]) = v;
        }
    }
    int wave = t >> 6, lane = t & 63;
    int r16 = lane & 15, quad = lane >> 4;
    const unsigned short* uh = ut + (size_t)h * BT + (size_t)b * Lseq;   // 4096 positions
    const unsigned short* wh = Wst + (size_t)h * 64 * 64;
    const unsigned short* vh = Vl + (size_t)h * 64 * 64;

    // ---- phase 1: local states Sl[cc][r] = sum_j Wst[r][j] u[cc*64+j] ----
    {
        int cc0 = wave * 16;
        float4v acc[4] = {};
#pragma unroll
        for (int k0 = 0; k0 < 64; k0 += 32) {
            short8 bf = *reinterpret_cast<const short8*>(uh + (size_t)(cc0 + r16) * 64 + k0 + quad * 8);
#pragma unroll
            for (int mt = 0; mt < 4; mt++) {
                short8 af = *reinterpret_cast<const short8*>(wh + (mt * 16 + r16) * 64 + k0 + quad * 8);
                acc[mt] = __builtin_amdgcn_mfma_f32_16x16x32_bf16(af, bf, acc[mt], 0, 0, 0);
            }
        }
        int cc = cc0 + r16;
#pragma unroll
        for (int mt = 0; mt < 4; mt++) {
            uint2 pk = pack4bf(acc[mt][0], acc[mt][1], acc[mt][2], acc[mt][3]);
            *(uint2*)(&Sl[cc][mt * 16 + quad * 4]) = pk;
        }
    }
    __syncthreads();

    // ---- phase 2: segmented scan; wave w owns chunks [16w, 16w+16) ----
    {
        int r = lane;
        int n = r >> 1;
        int base = ((layer * N2 + n) * 2) * H + h;
        float dre = dA[base], dim = dA[base + H];
        float e1 = expf(dre * 64.f);
        float Lr = e1 * cosf(dim * 64.f), Li = e1 * sinf(dim * 64.f);
        float Ls = (r & 1) ? Li : -Li;            // constant-split complex mult helper
        int c0 = wave * 16;

        // local serial scan (16 iters); E_loc kept in fp32 regs
        float eloc[16];
        float s = 0.f;
#pragma unroll
        for (int k = 0; k < 16; k++) {
            float p = bf2f(Sl[c0 + k][r]);
            eloc[k] = s;
            float sp = __shfl_xor(s, 1);
            s = fmaf(Lr, s, fmaf(Ls, sp, p));
        }
        Tw[wave][r] = s;
        __syncthreads();

        // carry: C_w = sum_{j<w} L16^{w-1-j} T_j,  L16 = Lc^16 = lambda^1024
        float e16 = expf(dre * 1024.f);
        float Lr16 = e16 * cosf(dim * 1024.f), Li16 = e16 * sinf(dim * 1024.f);
        float Ls16 = (r & 1) ? Li16 : -Li16;
        float C = 0.f;
        for (int j = 0; j < wave; j++) {          // wave-uniform branch
            float Tj = Tw[j][r];
            float Cp = __shfl_xor(C, 1);
            C = fmaf(Lr16, C, fmaf(Ls16, Cp, Tj));
        }
        float cpp = __shfl_xor(C, 1);             // partner component of C (loop-invariant)

        // apply: E[c0+k] = eloc[k] + (Lc^k (x) C); write in place to Sl
        float pw = (r & 1) ? 0.f : 1.f;           // Lc^0 = 1 + 0i (lane-split)
#pragma unroll
        for (int k = 0; k < 16; k++) {
            float pp = __shfl_xor(pw, 1);
            // split x split complex product: even: pw*C - pp*cpp ; odd: pp*C + pw*cpp
            float u1 = (r & 1) ? pp : pw;
            float u2 = (r & 1) ? pw : pp;
            float tt = u2 * cpp;
            float ead = fmaf(u1, C, (r & 1) ? tt : -tt);
            Sl[c0 + k][r] = f2bf(eloc[k] + ead);
            pw = fmaf(Lr, pw, Ls * pp);           // pw <- Lc (x) pw
        }
    }
    __syncthreads();

    // ---- phase 3: y = T*u + V*E, + D*u, gelu ----
    {
        int cc0 = wave * 16;
        float4v acc[4] = {};
#pragma unroll
        for (int k0 = 0; k0 < 64; k0 += 32) {    // Toeplitz part (u from global, L1-hot)
            short8 bf = *reinterpret_cast<const short8*>(uh + (size_t)(cc0 + r16) * 64 + k0 + quad * 8);
#pragma unroll
            for (int mt = 0; mt < 4; mt++) {
                short8 af = *reinterpret_cast<const short8*>(&T[mt * 16 + r16][k0 + quad * 8]);
                acc[mt] = __builtin_amdgcn_mfma_f32_16x16x32_bf16(af, bf, acc[mt], 0, 0, 0);
            }
        }
#pragma unroll
        for (int k0 = 0; k0 < 64; k0 += 32) {    // entering-state correction (E in Sl)
            short8 bf = *reinterpret_cast<const short8*>(&Sl[cc0 + r16][k0 + quad * 8]);
#pragma unroll
            for (int mt = 0; mt < 4; mt++) {
                short8 af = *reinterpret_cast<const short8*>(vh + (mt * 16 + r16) * 64 + k0 + quad * 8);
                acc[mt] = __builtin_amdgcn_mfma_f32_16x16x32_bf16(af, bf, acc[mt], 0, 0, 0);
            }
        }
        float Dh = Dp[layer * H + h];
        int cc = cc0 + r16;
        unsigned short* yh = yt + (size_t)h * BT + (size_t)b * Lseq;
#pragma unroll
        for (int mt = 0; mt < 4; mt++) {
            size_t p = (size_t)cc * 64 + mt * 16 + quad * 4;
            ushort4 uu = *(const ushort4*)(uh + p);
            float o[4];
#pragma unroll
            for (int r = 0; r < 4; r++) {
                float y = acc[mt][r] + Dh * bf2f(((const unsigned short*)&uu)[r]);
                o[r] = 0.5f * y * (1.0f + erff(y * 0.70710678118654752f));
            }
            *(uint2*)(yh + p) = pack4bf(o[0], o[1], o[2], o[3]);
        }
    }
}

// ---------- transpose y_t (H,BT bf16) -> ybf (BT,H bf16) ----------
__global__ __launch_bounds__(256) void transpose2_kernel(const unsigned short* __restrict__ yt,
                                                         unsigned short* __restrict__ yb) {
    __shared__ unsigned short tile[64][72];
    int bx = blockIdx.x;
    int pt = bx & 511, ht = bx >> 9;
    int p0 = pt * 64, h0 = ht * 64;
    int t = threadIdx.x;
    int jr = t & 7, ib = t >> 3;
#pragma unroll
    for (int pass = 0; pass < 2; pass++) {
        int i = ib + pass * 32;
        short8 v = *reinterpret_cast<const short8*>(yt + (size_t)(h0 + i) * BT + p0 + jr * 8);
        *reinterpret_cast<short8*>(&tile[i][jr * 8]) = v;   // 144B row stride -> 16B aligned
    }
    __syncthreads();
    int pp = t >> 2, hg = t & 3;
    short8 o0, o1;
#pragma unroll
    for (int r = 0; r < 8; r++) o0[r] = (short)tile[hg * 16 + r][pp];
#pragma unroll
    for (int r = 0; r < 8; r++) o1[r] = (short)tile[hg * 16 + 8 + r][pp];
    unsigned short* dst = yb + (size_t)(p0 + pp) * H + h0 + hg * 16;
    *reinterpret_cast<short8*>(dst) = o0;
    *reinterpret_cast<short8*>(dst + 8) = o1;
}

// ---------- fused 1x1 conv (LDS-tiled, bank-conflict-free swizzle) + bias + GLU ----------
// v2 (proven): triple-buffered LDS, depth-2 prefetch, raw s_barrier + counted vmcnt.
__global__ __launch_bounds__(256) void gemm_glu_kernel(const unsigned short* __restrict__ ybf,
                                                       const unsigned short* __restrict__ Wbf,
                                                       const float* __restrict__ bias,
                                                       unsigned short* __restrict__ yo, int layer) {
    __shared__ unsigned short As[3][128 * 32];
    __shared__ unsigned short Bs[3][128 * 32];
    int tid = threadIdx.x;
    int wave = tid >> 6, lane = tid & 63;
    int wr = wave >> 1, wc = wave & 1;
    int r16 = lane & 15, quad = lane >> 4;
    int m0 = blockIdx.x * 128;
    int o0 = blockIdx.y * 64;
    const unsigned short* Wl = Wbf + (size_t)layer * 2 * H * H;

    int srow = lane >> 2;
    int scol = ((lane & 3) ^ ((srow >> 1) & 3)) * 8;
    const unsigned short* aS0 = ybf + ((size_t)(m0 + wave * 16 + srow)) * H + scol;
    const unsigned short* aS1 = aS0 + (size_t)64 * H;
    const unsigned short* bSA = Wl + ((size_t)(o0 + wave * 16 + srow)) * H + scol;
    const unsigned short* bSG = bSA + (size_t)512 * H;
    const int aoff0 = (wave * 16) * 32;
    const int aoff1 = (64 + wave * 16) * 32;

    int rcol = (quad ^ ((r16 >> 1) & 3)) * 8;

    float4v acc_a[4][2] = {}, acc_g[4][2] = {};

    async_copy16(aS0,      &As[0][aoff0]);
    async_copy16(aS1,      &As[0][aoff1]);
    async_copy16(bSA,      &Bs[0][aoff0]);
    async_copy16(bSG,      &Bs[0][aoff1]);
    async_copy16(aS0 + 32, &As[1][aoff0]);
    async_copy16(aS1 + 32, &As[1][aoff1]);
    async_copy16(bSA + 32, &Bs[1][aoff0]);
    async_copy16(bSG + 32, &Bs[1][aoff1]);
    asm volatile("s_waitcnt vmcnt(4)" ::: "memory");
    __builtin_amdgcn_s_barrier();

#pragma unroll
    for (int ks = 0; ks < 16; ++ks) {
        const int b = ks % 3;
        if (ks < 14) {
            const int nb = (ks + 2) % 3;
            const int kn = (ks + 2) * 32;
            async_copy16(aS0 + kn, &As[nb][aoff0]);
            async_copy16(aS1 + kn, &As[nb][aoff1]);
            async_copy16(bSA + kn, &Bs[nb][aoff0]);
            async_copy16(bSG + kn, &Bs[nb][aoff1]);
        }

        short8 af[4], ba[2], bg[2];
#pragma unroll
        for (int mi = 0; mi < 4; mi++)
            af[mi] = *reinterpret_cast<const short8*>(&As[b][(wr * 64 + mi * 16 + r16) * 32 + rcol]);
#pragma unroll
        for (int ni = 0; ni < 2; ni++) {
            ba[ni] = *reinterpret_cast<const short8*>(&Bs[b][(wc * 32 + ni * 16 + r16) * 32 + rcol]);
            bg[ni] = *reinterpret_cast<const short8*>(&Bs[b][(64 + wc * 32 + ni * 16 + r16) * 32 + rcol]);
        }
#pragma unroll
        for (int mi = 0; mi < 4; mi++)
#pragma unroll
            for (int ni = 0; ni < 2; ni++) {
                acc_a[mi][ni] = __builtin_amdgcn_mfma_f32_16x16x32_bf16(af[mi], ba[ni], acc_a[mi][ni], 0, 0, 0);
                acc_g[mi][ni] = __builtin_amdgcn_mfma_f32_16x16x32_bf16(af[mi], bg[ni], acc_g[mi][ni], 0, 0, 0);
            }

        if (ks < 14) {
            asm volatile("s_waitcnt vmcnt(4) lgkmcnt(0)" ::: "memory");
            __builtin_amdgcn_s_barrier();
        } else if (ks == 14) {
            asm volatile("s_waitcnt vmcnt(0) lgkmcnt(0)" ::: "memory");
            __builtin_amdgcn_s_barrier();
        }
    }

    const float* bl = bias + layer * 2 * H;
#pragma unroll
    for (int ni = 0; ni < 2; ni++) {
        int o = o0 + wc * 32 + ni * 16 + r16;
        float ba_ = bl[o], bg_ = bl[H + o];
#pragma unroll
        for (int mi = 0; mi < 4; mi++)
#pragma unroll
            for (int r = 0; r < 4; r++) {
                int l = m0 + wr * 64 + mi * 16 + quad * 4 + r;
                float av = acc_a[mi][ni][r] + ba_;
                float gv = acc_g[mi][ni][r] + bg_;
                yo[(size_t)l * H + o] = f2bf(av * (1.0f / (1.0f + expf(-gv))));
            }
    }
}

// ---------- fused residual + LayerNorm + transpose-out (layers 0..2) ----------
__global__ __launch_bounds__(256) void ln_t_kernel(const unsigned short* __restrict__ yo,
                                                   const float* __restrict__ xf,
                                                   const unsigned short* __restrict__ xb,
                                                   const float* __restrict__ gamma,
                                                   const float* __restrict__ beta,
                                                   unsigned short* __restrict__ xR,
                                                   unsigned short* __restrict__ ut,
                                                   int in_f32, int layer) {
    __shared__ unsigned short tl[64][520];
    int t = threadIdx.x;
    int p0 = blockIdx.x * 64;
    int lane8 = t & 7;
    int rowb = t >> 3;
    const float* gl = gamma + layer * H;
    const float* bl = beta + layer * H;
#pragma unroll
    for (int rr = 0; rr < 2; rr++) {
        int row = rowb + rr * 32;
        size_t gbase = (size_t)(p0 + row) * H;
        float v[64];
        float s = 0.f, s2 = 0.f;
#pragma unroll
        for (int cc = 0; cc < 8; cc++) {
            int h0 = (lane8 + cc * 8) * 8;
            short8 yv = *reinterpret_cast<const short8*>(yo + gbase + h0);
            if (in_f32) {
                float4 x0 = *(const float4*)(xf + gbase + h0);
                float4 x1 = *(const float4*)(xf + gbase + h0 + 4);
                v[cc * 8 + 0] = bf2f((unsigned short)yv[0]) + x0.x;
                v[cc * 8 + 1] = bf2f((unsigned short)yv[1]) + x0.y;
                v[cc * 8 + 2] = bf2f((unsigned short)yv[2]) + x0.z;
                v[cc * 8 + 3] = bf2f((unsigned short)yv[3]) + x0.w;
                v[cc * 8 + 4] = bf2f((unsigned short)yv[4]) + x1.x;
                v[cc * 8 + 5] = bf2f((unsigned short)yv[5]) + x1.y;
                v[cc * 8 + 6] = bf2f((unsigned short)yv[6]) + x1.z;
                v[cc * 8 + 7] = bf2f((unsigned short)yv[7]) + x1.w;
            } else {
                short8 xv = *reinterpret_cast<const short8*>(xb + gbase + h0);
#pragma unroll
                for (int i = 0; i < 8; i++)
                    v[cc * 8 + i] = bf2f((unsigned short)yv[i]) + bf2f((unsigned short)xv[i]);
            }
#pragma unroll
            for (int i = 0; i < 8; i++) { s += v[cc * 8 + i]; s2 = fmaf(v[cc * 8 + i], v[cc * 8 + i], s2); }
        }
        s += __shfl_xor(s, 1);  s2 += __shfl_xor(s2, 1);
        s += __shfl_xor(s, 2);  s2 += __shfl_xor(s2, 2);
        s += __shfl_xor(s, 4);  s2 += __shfl_xor(s2, 4);
        float mu = s * (1.0f / H);
        float var = s2 * (1.0f / H) - mu * mu;
        float inv = rsqrtf(var + 1e-5f);
#pragma unroll
        for (int cc = 0; cc < 8; cc++) {
            int h0 = (lane8 + cc * 8) * 8;
            float4 g0 = *(const float4*)(gl + h0);
            float4 g1 = *(const float4*)(gl + h0 + 4);
            float4 b0 = *(const float4*)(bl + h0);
            float4 b1 = *(const float4*)(bl + h0 + 4);
            short8 pk;
            pk[0] = (short)f2bf((v[cc * 8 + 0] - mu) * inv * g0.x + b0.x);
            pk[1] = (short)f2bf((v[cc * 8 + 1] - mu) * inv * g0.y + b0.y);
            pk[2] = (short)f2bf((v[cc * 8 + 2] - mu) * inv * g0.z + b0.z);
            pk[3] = (short)f2bf((v[cc * 8 + 3] - mu) * inv * g0.w + b0.w);
            pk[4] = (short)f2bf((v[cc * 8 + 4] - mu) * inv * g1.x + b1.x);
            pk[5] = (short)f2bf((v[cc * 8 + 5] - mu) * inv * g1.y + b1.y);
            pk[6] = (short)f2bf((v[cc * 8 + 6] - mu) * inv * g1.z + b1.z);
            pk[7] = (short)f2bf((v[cc * 8 + 7] - mu) * inv * g1.w + b1.w);
            *reinterpret_cast<short8*>(xR + gbase + h0) = pk;
            *reinterpret_cast<short8*>(&tl[row][h0]) = pk;
        }
    }
    __syncthreads();
#pragma unroll
    for (int hh = 0; hh < 2; hh++) {
        int h = t + hh * 256;
        unsigned short* dst = ut + (size_t)h * BT + p0;
#pragma unroll
        for (int pc = 0; pc < 8; pc++) {
            short8 o;
#pragma unroll
            for (int e = 0; e < 8; e++) o[e] = (short)tl[pc * 8 + e][h];
            *reinterpret_cast<short8*>(dst + pc * 8) = o;
        }
    }
}

// ---------- residual + LayerNorm (final layer: fp32 out) ----------
__global__ __launch_bounds__(256) void ln_kernel(const unsigned short* __restrict__ yo,
                                                 const float* __restrict__ xf,
                                                 const unsigned short* __restrict__ xb,
                                                 const float* __restrict__ gamma, const float* __restrict__ beta,
                                                 float* __restrict__ of, unsigned short* __restrict__ ob,
                                                 int in_f32, int out_f32, int layer) {
    int wave = threadIdx.x >> 6, lane = threadIdx.x & 63;
    size_t row = (size_t)blockIdx.x * 4 + wave;
    const unsigned short* yp = yo + row * H + lane * 8;
    short8 yv = *reinterpret_cast<const short8*>(yp);
    float v[8];
    if (in_f32) {
        const float* xp = xf + row * H + lane * 8;
        float4 x0 = *(const float4*)(xp);
        float4 x1 = *(const float4*)(xp + 4);
        v[0] = bf2f((unsigned short)yv[0]) + x0.x; v[1] = bf2f((unsigned short)yv[1]) + x0.y;
        v[2] = bf2f((unsigned short)yv[2]) + x0.z; v[3] = bf2f((unsigned short)yv[3]) + x0.w;
        v[4] = bf2f((unsigned short)yv[4]) + x1.x; v[5] = bf2f((unsigned short)yv[5]) + x1.y;
        v[6] = bf2f((unsigned short)yv[6]) + x1.z; v[7] = bf2f((unsigned short)yv[7]) + x1.w;
    } else {
        const unsigned short* xp = xb + row * H + lane * 8;
        short8 xv = *reinterpret_cast<const short8*>(xp);
#pragma unroll
        for (int i = 0; i < 8; i++)
            v[i] = bf2f((unsigned short)yv[i]) + bf2f((unsigned short)xv[i]);
    }
    float s = 0.f, s2 = 0.f;
#pragma unroll
    for (int i = 0; i < 8; i++) { s += v[i]; s2 = fmaf(v[i], v[i], s2); }
#pragma unroll
    for (int off = 32; off; off >>= 1) {
        s += __shfl_xor(s, off);
        s2 += __shfl_xor(s2, off);
    }
    float mu = s * (1.0f / H);
    float var = s2 * (1.0f / H) - mu * mu;
    float inv = rsqrtf(var + 1e-5f);
    const float* gl = gamma + layer * H + lane * 8;
    const float* bl = beta + layer * H + lane * 8;
    float o[8];
#pragma unroll
    for (int i = 0; i < 8; i++)
        o[i] = (v[i] - mu) * inv * gl[i] + bl[i];
    if (out_f32) {
        float* op = of + row * H + lane * 8;
        *(float4*)(op) = make_float4(o[0], o[1], o[2], o[3]);
        *(float4*)(op + 4) = make_float4(o[4], o[5], o[6], o[7]);
    } else {
        unsigned short* op = ob + row * H + lane * 8;
        uint2 p0 = pack4bf(o[0], o[1], o[2], o[3]);
        uint2 p1 = pack4bf(o[4], o[5], o[6], o[7]);
        *(uint2*)(op) = p0;
        *(uint2*)(op + 4) = p1;
    }
}

extern "C" void kernel_launch(void* const* d_in, const int* in_sizes, int n_in,
                              void* d_out, int out_size, void* d_ws, size_t ws_size,
                              hipStream_t stream) {
    const float* x          = (const float*)d_in[0];
    const float* log_dt     = (const float*)d_in[1];
    const float* A_imag     = (const float*)d_in[2];
    const float* log_A_real = (const float*)d_in[3];
    const float* C          = (const float*)d_in[4];
    const float* D          = (const float*)d_in[5];
    const float* W          = (const float*)d_in[6];
    const float* bias       = (const float*)d_in[7];
    const float* gamma      = (const float*)d_in[8];
    const float* beta       = (const float*)d_in[9];

    char* ws = (char*)d_ws;
    unsigned short* xR   = (unsigned short*)(ws + 0);           // bf16 residual stream
    unsigned short* Vbuf = (unsigned short*)(ws + 67108864);    // V (freed Sloc slot)
    unsigned short* u_t  = (unsigned short*)(ws + 100663296);
    unsigned short* ybf  = (unsigned short*)(ws + 100663296);   // overlay: after ssm, u_t dead
    unsigned short* y_t  = (unsigned short*)(ws + 134217728);
    unsigned short* yo   = (unsigned short*)(ws + 134217728);   // overlay: after transpose2, y_t dead
    unsigned short* Wbf  = (unsigned short*)(ws + 167772160);
    unsigned short* Wstb = (unsigned short*)(ws + 171966464);   // Wstate
    unsigned short* kmat = (unsigned short*)(ws + 176160768);
    float*          dA   = (float*)(ws + 176422912);
    float*          Ct   = (float*)(ws + 176947200);
    float* xout_final    = (float*)d_out;

    wconv_kernel<<<NL * 2 * H * H / 256, 256, 0, stream>>>(W, Wbf);
    params_kernel<<<NL * N2 * H / 256, 256, 0, stream>>>(log_dt, A_imag, log_A_real, C, dA, Ct);
    kergen_k_kernel<<<NL * H * 64 / 256, 256, 0, stream>>>(dA, Ct, kmat);

    for (int layer = 0; layer < NL; ++layer) {
        if (layer == 0)
            t1_f32_kernel<<<4096, 256, 0, stream>>>(x, u_t);
        // layers >=1: u_t was already produced (transposed) by ln_t of the previous layer
        kergenW_kernel<<<H * 64 * 64 / 256, 256, 0, stream>>>(dA, Wstb, layer);
        kergenV_kernel<<<H * 64 * 64 / 256, 256, 0, stream>>>(dA, Ct, Vbuf, layer);
        ssm_kernel<<<dim3(H, Bsz), 256, 0, stream>>>(u_t, kmat, Wstb, Vbuf, dA, D, y_t, layer);
        transpose2_kernel<<<4096, 256, 0, stream>>>(y_t, ybf);
        gemm_glu_kernel<<<dim3(BT / 128, H / 64), 256, 0, stream>>>(ybf, Wbf, bias, yo, layer);
        if (layer < NL - 1) {
            ln_t_kernel<<<BT / 64, 256, 0, stream>>>(yo, x, xR, gamma, beta,
                                                     xR, u_t, (layer == 0) ? 1 : 0, layer);
        } else {
            ln_kernel<<<BT / 4, 256, 0, stream>>>(yo, x, xR, gamma, beta,
                                                  xout_final, xR, 0, 1, layer);
        }
    }
}

// Round 8
// 831.958 us; speedup vs baseline: 1.1488x; 1.0075x over previous
//
#include <hip/hip_runtime.h>
#include <hip/hip_bf16.h>
#include <math.h>

#define H 512
#define NL 4
#define N2 32
#define Bsz 8
#define Lseq 4096
#define BT (Bsz*Lseq)        // 32768 total positions
#define LC2 64               // chunk length
#define NCC (BT/LC2)         // 512 chunks total
#define CPB (Lseq/LC2)       // 64 chunks per batch element

typedef __attribute__((ext_vector_type(8))) short short8;   // 8 bf16
typedef __attribute__((ext_vector_type(4))) float float4v;

// ---------------- ws layout (bytes) ----------------
// 0         : xR   (bf16 BT*H residual)        33554432
// 67108864  : Vbuf (bf16 H*64*64, V)            4194304
// 100663296 : u_t  (bf16 H*BT) / ybf overlay   33554432
// 134217728 : y_t  (bf16 H*BT) / yo overlay    33554432
// 167772160 : Wbf  (bf16 NL*2H*H)               4194304
// 171966464 : Wst  (bf16 H*64*64, Wstate)       4194304
// 176160768 : kmat (bf16 NL*H*64)                262144
// 176422912 : dA   (fp32 NL*N2*2*H)              524288
// 176947200 : Ct   (fp32 NL*N2*2*H)              524288

__device__ __forceinline__ float bf2f(unsigned short u) {
    union { unsigned int i; float f; } x; x.i = ((unsigned int)u) << 16; return x.f;
}
__device__ __forceinline__ unsigned short f2bf(float f) {
    union { float f; unsigned int i; } x; x.f = f;
    unsigned int u = x.i + 0x7fff + ((x.i >> 16) & 1);
    return (unsigned short)(u >> 16);
}
__device__ __forceinline__ uint2 pack4bf(float a, float b, float c, float d) {
    uint2 r;
    r.x = (unsigned)f2bf(a) | ((unsigned)f2bf(b) << 16);
    r.y = (unsigned)f2bf(c) | ((unsigned)f2bf(d) << 16);
    return r;
}
__device__ __forceinline__ void async_copy16(const void* g, void* l) {
    __builtin_amdgcn_global_load_lds(
        (const __attribute__((address_space(1))) void*)g,
        (__attribute__((address_space(3))) void*)l, 16, 0, 0);
}

// ---------- convert W to bf16 ----------
__global__ void wconv_kernel(const float* __restrict__ W, unsigned short* __restrict__ Wbf) {
    int tid = blockIdx.x * 256 + threadIdx.x;
    Wbf[tid] = f2bf(W[tid]);
}

// ---------- per-(layer,n,h): dA = log(lambda), Ct = 2C(lambda-1)/A ----------
__global__ void params_kernel(const float* __restrict__ log_dt, const float* __restrict__ A_imag,
                              const float* __restrict__ log_A_real, const float* __restrict__ Cin,
                              float* __restrict__ dA, float* __restrict__ Ct) {
    int tid = blockIdx.x * 256 + threadIdx.x;   // ((layer*N2+n)*H + h)
    int h = tid % H;
    int n = (tid / H) % N2;
    int layer = tid / (H * N2);
    float dt = expf(log_dt[layer * H + h]);
    int pidx = (layer * H + h) * N2 + n;
    float Are = -expf(log_A_real[pidx]);
    float Aim = A_imag[pidx];
    float dre = Are * dt, dim = Aim * dt;
    float er = expf(dre);
    float lre = er * cosf(dim), lim = er * sinf(dim);
    float nre = lre - 1.0f, nim = lim;
    float inv = 1.0f / (Are * Are + Aim * Aim);
    float tre = (nre * Are + nim * Aim) * inv;
    float tim = (nim * Are - nre * Aim) * inv;
    float Ccre = Cin[pidx * 2], Ccim = Cin[pidx * 2 + 1];
    int oidx = ((layer * N2 + n) * 2) * H + h;
    dA[oidx] = dre;  dA[oidx + H] = dim;
    Ct[oidx] = 2.0f * (Ccre * tre - Ccim * tim);
    Ct[oidx + H] = 2.0f * (Ccre * tim + Ccim * tre);
}

// ---------- kernels k[d] = Re sum_n Ct_n lambda_n^d, all layers ----------
__global__ void kergen_k_kernel(const float* __restrict__ dA, const float* __restrict__ Ct,
                                unsigned short* __restrict__ kmat) {
    int t = blockIdx.x * 256 + threadIdx.x;     // (layer*H + h)*64 + d
    int d = t & 63;
    int h = (t >> 6) & (H - 1);
    int layer = t >> 15;
    float fd = (float)d;
    float sum = 0.f;
    for (int n = 0; n < N2; n++) {
        int base = ((layer * N2 + n) * 2) * H + h;
        float dre = dA[base], dim = dA[base + H];
        float Ctr = Ct[base], Cti = Ct[base + H];
        float e = expf(dre * fd);
        sum += Ctr * e * cosf(dim * fd) - Cti * e * sinf(dim * fd);
    }
    kmat[t] = f2bf(sum);
}

// ---------- merged Wstate + V generation (same grid decomposition) ----------
// W part: t=(h*64+r)*64+j : r=2n -> Re(l^(63-j)), r=2n+1 -> Im
// V part: t=(h*64+l)*64+c2: c2=2n -> Re(Ct l^(l+1)), c2=2n+1 -> -Im
__global__ void kergenWV_kernel(const float* __restrict__ dA, const float* __restrict__ Ct,
                                unsigned short* __restrict__ Wst, unsigned short* __restrict__ Vl,
                                int layer) {
    int t = blockIdx.x * 256 + threadIdx.x;
    int h = t >> 12;
    {   // Wstate element
        int j = t & 63;
        int r = (t >> 6) & 63;
        int n = r >> 1;
        int base = ((layer * N2 + n) * 2) * H + h;
        float dre = dA[base], dim = dA[base + H];
        float p = (float)(63 - j);
        float e = expf(dre * p);
        Wst[t] = f2bf((r & 1) ? e * sinf(dim * p) : e * cosf(dim * p));
    }
    {   // V element
        int c2 = t & 63;
        int l = (t >> 6) & 63;
        int n = c2 >> 1;
        int base = ((layer * N2 + n) * 2) * H + h;
        float dre = dA[base], dim = dA[base + H];
        float Ctr = Ct[base], Cti = Ct[base + H];
        float q = (float)(l + 1);
        float e = expf(dre * q);
        float ar = e * cosf(dim * q), ai = e * sinf(dim * q);
        float vre = Ctr * ar - Cti * ai;
        float vim = Ctr * ai + Cti * ar;
        Vl[t] = f2bf((c2 & 1) ? -vim : vre);
    }
}

// ---------- transpose x fp32 (BT,H) -> u_t bf16 (H,BT)  [layer 0 only] ----------
__global__ __launch_bounds__(256) void t1_f32_kernel(const float* __restrict__ xi,
                                                     unsigned short* __restrict__ ut) {
    __shared__ float tile[64][68];
    int bx = blockIdx.x;
    int pt = bx & 511, ht = bx >> 9;
    int p0 = pt * 64, h0 = ht * 64;
    int t = threadIdx.x;
    int jr = t & 15, ib = t >> 4;
#pragma unroll
    for (int pass = 0; pass < 4; pass++) {
        int i = ib + pass * 16;
        float4 v = *(const float4*)(xi + (size_t)(p0 + i) * H + h0 + jr * 4);
        *(float4*)(&tile[i][jr * 4]) = v;   // 272B row stride -> 16B aligned
    }
    __syncthreads();
#pragma unroll
    for (int pass = 0; pass < 4; pass++) {
        int i2 = ib + pass * 16;
        int j2 = jr * 4;
        uint2 pk = pack4bf(tile[j2][i2], tile[j2 + 1][i2], tile[j2 + 2][i2], tile[j2 + 3][i2]);
        *(uint2*)(ut + (size_t)(h0 + i2) * BT + p0 + j2) = pk;
    }
}

// ---------- FUSED SSM v3: segmented scan; gelu REMOVED (moved to gelu_t2) ----------
// One block per (h, batch). Output y_t = conv + D*u (pre-gelu, bf16).
__global__ __launch_bounds__(256) void ssm_kernel(const unsigned short* __restrict__ ut,
                                                  const unsigned short* __restrict__ kmat,
                                                  const unsigned short* __restrict__ Wst,
                                                  const unsigned short* __restrict__ Vl,
                                                  const float* __restrict__ dA,
                                                  const float* __restrict__ Dp,
                                                  unsigned short* __restrict__ yt, int layer) {
    __shared__ unsigned short T[64][72];    // Toeplitz
    __shared__ unsigned short Sl[64][72];   // local states -> (in place) entering states
    __shared__ float Tw[4][64];             // fp32 per-wave segment totals
    int h = blockIdx.x, b = blockIdx.y;
    int t = threadIdx.x;
    const unsigned short* km = kmat + ((size_t)layer * H + h) * 64;
    {   // build lower-triangular Toeplitz T[l][j] = k[l-j]
        int l = t >> 2, j0 = (t & 3) * 16;
#pragma unroll
        for (int g = 0; g < 2; g++) {
            short8 v;
#pragma unroll
            for (int e = 0; e < 8; e++) {
                int j = j0 + g * 8 + e;
                v[e] = (j <= l) ? (short)km[l - j] : (short)0;
            }
            *reinterpret_cast<short8*>(&T[l][j0 + g * 8]) = v;
        }
    }
    int wave = t >> 6, lane = t & 63;
    int r16 = lane & 15, quad = lane >> 4;
    const unsigned short* uh = ut + (size_t)h * BT + (size_t)b * Lseq;   // 4096 positions
    const unsigned short* wh = Wst + (size_t)h * 64 * 64;
    const unsigned short* vh = Vl + (size_t)h * 64 * 64;

    // ---- phase 1: local states Sl[cc][r] = sum_j Wst[r][j] u[cc*64+j] ----
    {
        int cc0 = wave * 16;
        float4v acc[4] = {};
#pragma unroll
        for (int k0 = 0; k0 < 64; k0 += 32) {
            short8 bf = *reinterpret_cast<const short8*>(uh + (size_t)(cc0 + r16) * 64 + k0 + quad * 8);
#pragma unroll
            for (int mt = 0; mt < 4; mt++) {
                short8 af = *reinterpret_cast<const short8*>(wh + (mt * 16 + r16) * 64 + k0 + quad * 8);
                acc[mt] = __builtin_amdgcn_mfma_f32_16x16x32_bf16(af, bf, acc[mt], 0, 0, 0);
            }
        }
        int cc = cc0 + r16;
#pragma unroll
        for (int mt = 0; mt < 4; mt++) {
            uint2 pk = pack4bf(acc[mt][0], acc[mt][1], acc[mt][2], acc[mt][3]);
            *(uint2*)(&Sl[cc][mt * 16 + quad * 4]) = pk;
        }
    }
    __syncthreads();

    // ---- phase 2: segmented scan; wave w owns chunks [16w, 16w+16) ----
    {
        int r = lane;
        int n = r >> 1;
        int base = ((layer * N2 + n) * 2) * H + h;
        float dre = dA[base], dim = dA[base + H];
        float e1 = expf(dre * 64.f);
        float Lr = e1 * cosf(dim * 64.f), Li = e1 * sinf(dim * 64.f);
        float Ls = (r & 1) ? Li : -Li;            // constant-split complex mult helper
        int c0 = wave * 16;

        float eloc[16];
        float s = 0.f;
#pragma unroll
        for (int k = 0; k < 16; k++) {
            float p = bf2f(Sl[c0 + k][r]);
            eloc[k] = s;
            float sp = __shfl_xor(s, 1);
            s = fmaf(Lr, s, fmaf(Ls, sp, p));
        }
        Tw[wave][r] = s;
        __syncthreads();

        // carry: C_w = sum_{j<w} L16^{w-1-j} T_j,  L16 = Lc^16 = lambda^1024
        float e16 = expf(dre * 1024.f);
        float Lr16 = e16 * cosf(dim * 1024.f), Li16 = e16 * sinf(dim * 1024.f);
        float Ls16 = (r & 1) ? Li16 : -Li16;
        float C = 0.f;
        for (int j = 0; j < wave; j++) {          // wave-uniform branch
            float Tj = Tw[j][r];
            float Cp = __shfl_xor(C, 1);
            C = fmaf(Lr16, C, fmaf(Ls16, Cp, Tj));
        }
        float cpp = __shfl_xor(C, 1);             // partner component of C (loop-invariant)

        // apply: E[c0+k] = eloc[k] + (Lc^k (x) C); write in place to Sl
        float pw = (r & 1) ? 0.f : 1.f;           // Lc^0 = 1 + 0i (lane-split)
#pragma unroll
        for (int k = 0; k < 16; k++) {
            float pp = __shfl_xor(pw, 1);
            float u1 = (r & 1) ? pp : pw;
            float u2 = (r & 1) ? pw : pp;
            float tt = u2 * cpp;
            float ead = fmaf(u1, C, (r & 1) ? tt : -tt);
            Sl[c0 + k][r] = f2bf(eloc[k] + ead);
            pw = fmaf(Lr, pw, Ls * pp);           // pw <- Lc (x) pw
        }
    }
    __syncthreads();

    // ---- phase 3: y = T*u + V*E + D*u (NO gelu here) ----
    {
        int cc0 = wave * 16;
        float4v acc[4] = {};
#pragma unroll
        for (int k0 = 0; k0 < 64; k0 += 32) {    // Toeplitz part (u from global, L1-hot)
            short8 bf = *reinterpret_cast<const short8*>(uh + (size_t)(cc0 + r16) * 64 + k0 + quad * 8);
#pragma unroll
            for (int mt = 0; mt < 4; mt++) {
                short8 af = *reinterpret_cast<const short8*>(&T[mt * 16 + r16][k0 + quad * 8]);
                acc[mt] = __builtin_amdgcn_mfma_f32_16x16x32_bf16(af, bf, acc[mt], 0, 0, 0);
            }
        }
#pragma unroll
        for (int k0 = 0; k0 < 64; k0 += 32) {    // entering-state correction (E in Sl)
            short8 bf = *reinterpret_cast<const short8*>(&Sl[cc0 + r16][k0 + quad * 8]);
#pragma unroll
            for (int mt = 0; mt < 4; mt++) {
                short8 af = *reinterpret_cast<const short8*>(vh + (mt * 16 + r16) * 64 + k0 + quad * 8);
                acc[mt] = __builtin_amdgcn_mfma_f32_16x16x32_bf16(af, bf, acc[mt], 0, 0, 0);
            }
        }
        float Dh = Dp[layer * H + h];
        int cc = cc0 + r16;
        unsigned short* yh = yt + (size_t)h * BT + (size_t)b * Lseq;
#pragma unroll
        for (int mt = 0; mt < 4; mt++) {
            size_t p = (size_t)cc * 64 + mt * 16 + quad * 4;
            ushort4 uu = *(const ushort4*)(uh + p);
            float o0 = acc[mt][0] + Dh * bf2f(uu.x);
            float o1 = acc[mt][1] + Dh * bf2f(uu.y);
            float o2 = acc[mt][2] + Dh * bf2f(uu.z);
            float o3 = acc[mt][3] + Dh * bf2f(uu.w);
            *(uint2*)(yh + p) = pack4bf(o0, o1, o2, o3);
        }
    }
}

// ---------- fused GELU + transpose: y_t (H,BT pre-gelu) -> ybf (BT,H gelu'd) ----------
__global__ __launch_bounds__(256) void gelu_t2_kernel(const unsigned short* __restrict__ yt,
                                                      unsigned short* __restrict__ yb) {
    __shared__ unsigned short tile[64][72];
    int bx = blockIdx.x;
    int pt = bx & 511, ht = bx >> 9;
    int p0 = pt * 64, h0 = ht * 64;
    int t = threadIdx.x;
    int jr = t & 7, ib = t >> 3;
#pragma unroll
    for (int pass = 0; pass < 2; pass++) {
        int i = ib + pass * 32;
        short8 v = *reinterpret_cast<const short8*>(yt + (size_t)(h0 + i) * BT + p0 + jr * 8);
        short8 w;
#pragma unroll
        for (int e = 0; e < 8; e++) {
            float y = bf2f((unsigned short)v[e]);
            float g = 0.5f * y * (1.0f + erff(y * 0.70710678118654752f));
            w[e] = (short)f2bf(g);
        }
        *reinterpret_cast<short8*>(&tile[i][jr * 8]) = w;
    }
    __syncthreads();
    int pp = t >> 2, hg = t & 3;
    short8 o0, o1;
#pragma unroll
    for (int r = 0; r < 8; r++) o0[r] = (short)tile[hg * 16 + r][pp];
#pragma unroll
    for (int r = 0; r < 8; r++) o1[r] = (short)tile[hg * 16 + 8 + r][pp];
    unsigned short* dst = yb + (size_t)(p0 + pp) * H + h0 + hg * 16;
    *reinterpret_cast<short8*>(dst) = o0;
    *reinterpret_cast<short8*>(dst + 8) = o1;
}

// ---------- fused 1x1 conv (LDS-tiled, bank-conflict-free swizzle) + bias + GLU ----------
// v2 (proven): triple-buffered LDS, depth-2 prefetch, raw s_barrier + counted vmcnt.
__global__ __launch_bounds__(256) void gemm_glu_kernel(const unsigned short* __restrict__ ybf,
                                                       const unsigned short* __restrict__ Wbf,
                                                       const float* __restrict__ bias,
                                                       unsigned short* __restrict__ yo, int layer) {
    __shared__ unsigned short As[3][128 * 32];
    __shared__ unsigned short Bs[3][128 * 32];
    int tid = threadIdx.x;
    int wave = tid >> 6, lane = tid & 63;
    int wr = wave >> 1, wc = wave & 1;
    int r16 = lane & 15, quad = lane >> 4;
    int m0 = blockIdx.x * 128;
    int o0 = blockIdx.y * 64;
    const unsigned short* Wl = Wbf + (size_t)layer * 2 * H * H;

    int srow = lane >> 2;
    int scol = ((lane & 3) ^ ((srow >> 1) & 3)) * 8;
    const unsigned short* aS0 = ybf + ((size_t)(m0 + wave * 16 + srow)) * H + scol;
    const unsigned short* aS1 = aS0 + (size_t)64 * H;
    const unsigned short* bSA = Wl + ((size_t)(o0 + wave * 16 + srow)) * H + scol;
    const unsigned short* bSG = bSA + (size_t)512 * H;
    const int aoff0 = (wave * 16) * 32;
    const int aoff1 = (64 + wave * 16) * 32;

    int rcol = (quad ^ ((r16 >> 1) & 3)) * 8;

    float4v acc_a[4][2] = {}, acc_g[4][2] = {};

    async_copy16(aS0,      &As[0][aoff0]);
    async_copy16(aS1,      &As[0][aoff1]);
    async_copy16(bSA,      &Bs[0][aoff0]);
    async_copy16(bSG,      &Bs[0][aoff1]);
    async_copy16(aS0 + 32, &As[1][aoff0]);
    async_copy16(aS1 + 32, &As[1][aoff1]);
    async_copy16(bSA + 32, &Bs[1][aoff0]);
    async_copy16(bSG + 32, &Bs[1][aoff1]);
    asm volatile("s_waitcnt vmcnt(4)" ::: "memory");
    __builtin_amdgcn_s_barrier();

#pragma unroll
    for (int ks = 0; ks < 16; ++ks) {
        const int b = ks % 3;
        if (ks < 14) {
            const int nb = (ks + 2) % 3;
            const int kn = (ks + 2) * 32;
            async_copy16(aS0 + kn, &As[nb][aoff0]);
            async_copy16(aS1 + kn, &As[nb][aoff1]);
            async_copy16(bSA + kn, &Bs[nb][aoff0]);
            async_copy16(bSG + kn, &Bs[nb][aoff1]);
        }

        short8 af[4], ba[2], bg[2];
#pragma unroll
        for (int mi = 0; mi < 4; mi++)
            af[mi] = *reinterpret_cast<const short8*>(&As[b][(wr * 64 + mi * 16 + r16) * 32 + rcol]);
#pragma unroll
        for (int ni = 0; ni < 2; ni++) {
            ba[ni] = *reinterpret_cast<const short8*>(&Bs[b][(wc * 32 + ni * 16 + r16) * 32 + rcol]);
            bg[ni] = *reinterpret_cast<const short8*>(&Bs[b][(64 + wc * 32 + ni * 16 + r16) * 32 + rcol]);
        }
#pragma unroll
        for (int mi = 0; mi < 4; mi++)
#pragma unroll
            for (int ni = 0; ni < 2; ni++) {
                acc_a[mi][ni] = __builtin_amdgcn_mfma_f32_16x16x32_bf16(af[mi], ba[ni], acc_a[mi][ni], 0, 0, 0);
                acc_g[mi][ni] = __builtin_amdgcn_mfma_f32_16x16x32_bf16(af[mi], bg[ni], acc_g[mi][ni], 0, 0, 0);
            }

        if (ks < 14) {
            asm volatile("s_waitcnt vmcnt(4) lgkmcnt(0)" ::: "memory");
            __builtin_amdgcn_s_barrier();
        } else if (ks == 14) {
            asm volatile("s_waitcnt vmcnt(0) lgkmcnt(0)" ::: "memory");
            __builtin_amdgcn_s_barrier();
        }
    }

    const float* bl = bias + layer * 2 * H;
#pragma unroll
    for (int ni = 0; ni < 2; ni++) {
        int o = o0 + wc * 32 + ni * 16 + r16;
        float ba_ = bl[o], bg_ = bl[H + o];
#pragma unroll
        for (int mi = 0; mi < 4; mi++)
#pragma unroll
            for (int r = 0; r < 4; r++) {
                int l = m0 + wr * 64 + mi * 16 + quad * 4 + r;
                float av = acc_a[mi][ni][r] + ba_;
                float gv = acc_g[mi][ni][r] + bg_;
                yo[(size_t)l * H + o] = f2bf(av * (1.0f / (1.0f + expf(-gv))));
            }
    }
}

// ---------- fused residual + LayerNorm + transpose-out (layers 0..2) ----------
__global__ __launch_bounds__(256) void ln_t_kernel(const unsigned short* __restrict__ yo,
                                                   const float* __restrict__ xf,
                                                   const unsigned short* __restrict__ xb,
                                                   const float* __restrict__ gamma,
                                                   const float* __restrict__ beta,
                                                   unsigned short* __restrict__ xR,
                                                   unsigned short* __restrict__ ut,
                                                   int in_f32, int layer) {
    __shared__ unsigned short tl[64][520];
    int t = threadIdx.x;
    int p0 = blockIdx.x * 64;
    int lane8 = t & 7;
    int rowb = t >> 3;
    const float* gl = gamma + layer * H;
    const float* bl = beta + layer * H;
#pragma unroll
    for (int rr = 0; rr < 2; rr++) {
        int row = rowb + rr * 32;
        size_t gbase = (size_t)(p0 + row) * H;
        float v[64];
        float s = 0.f, s2 = 0.f;
#pragma unroll
        for (int cc = 0; cc < 8; cc++) {
            int h0 = (lane8 + cc * 8) * 8;
            short8 yv = *reinterpret_cast<const short8*>(yo + gbase + h0);
            if (in_f32) {
                float4 x0 = *(const float4*)(xf + gbase + h0);
                float4 x1 = *(const float4*)(xf + gbase + h0 + 4);
                v[cc * 8 + 0] = bf2f((unsigned short)yv[0]) + x0.x;
                v[cc * 8 + 1] = bf2f((unsigned short)yv[1]) + x0.y;
                v[cc * 8 + 2] = bf2f((unsigned short)yv[2]) + x0.z;
                v[cc * 8 + 3] = bf2f((unsigned short)yv[3]) + x0.w;
                v[cc * 8 + 4] = bf2f((unsigned short)yv[4]) + x1.x;
                v[cc * 8 + 5] = bf2f((unsigned short)yv[5]) + x1.y;
                v[cc * 8 + 6] = bf2f((unsigned short)yv[6]) + x1.z;
                v[cc * 8 + 7] = bf2f((unsigned short)yv[7]) + x1.w;
            } else {
                short8 xv = *reinterpret_cast<const short8*>(xb + gbase + h0);
#pragma unroll
                for (int i = 0; i < 8; i++)
                    v[cc * 8 + i] = bf2f((unsigned short)yv[i]) + bf2f((unsigned short)xv[i]);
            }
#pragma unroll
            for (int i = 0; i < 8; i++) { s += v[cc * 8 + i]; s2 = fmaf(v[cc * 8 + i], v[cc * 8 + i], s2); }
        }
        s += __shfl_xor(s, 1);  s2 += __shfl_xor(s2, 1);
        s += __shfl_xor(s, 2);  s2 += __shfl_xor(s2, 2);
        s += __shfl_xor(s, 4);  s2 += __shfl_xor(s2, 4);
        float mu = s * (1.0f / H);
        float var = s2 * (1.0f / H) - mu * mu;
        float inv = rsqrtf(var + 1e-5f);
#pragma unroll
        for (int cc = 0; cc < 8; cc++) {
            int h0 = (lane8 + cc * 8) * 8;
            float4 g0 = *(const float4*)(gl + h0);
            float4 g1 = *(const float4*)(gl + h0 + 4);
            float4 b0 = *(const float4*)(bl + h0);
            float4 b1 = *(const float4*)(bl + h0 + 4);
            short8 pk;
            pk[0] = (short)f2bf((v[cc * 8 + 0] - mu) * inv * g0.x + b0.x);
            pk[1] = (short)f2bf((v[cc * 8 + 1] - mu) * inv * g0.y + b0.y);
            pk[2] = (short)f2bf((v[cc * 8 + 2] - mu) * inv * g0.z + b0.z);
            pk[3] = (short)f2bf((v[cc * 8 + 3] - mu) * inv * g0.w + b0.w);
            pk[4] = (short)f2bf((v[cc * 8 + 4] - mu) * inv * g1.x + b1.x);
            pk[5] = (short)f2bf((v[cc * 8 + 5] - mu) * inv * g1.y + b1.y);
            pk[6] = (short)f2bf((v[cc * 8 + 6] - mu) * inv * g1.z + b1.z);
            pk[7] = (short)f2bf((v[cc * 8 + 7] - mu) * inv * g1.w + b1.w);
            *reinterpret_cast<short8*>(xR + gbase + h0) = pk;
            *reinterpret_cast<short8*>(&tl[row][h0]) = pk;
        }
    }
    __syncthreads();
#pragma unroll
    for (int hh = 0; hh < 2; hh++) {
        int h = t + hh * 256;
        unsigned short* dst = ut + (size_t)h * BT + p0;
#pragma unroll
        for (int pc = 0; pc < 8; pc++) {
            short8 o;
#pragma unroll
            for (int e = 0; e < 8; e++) o[e] = (short)tl[pc * 8 + e][h];
            *reinterpret_cast<short8*>(dst + pc * 8) = o;
        }
    }
}

// ---------- residual + LayerNorm (final layer: fp32 out) ----------
__global__ __launch_bounds__(256) void ln_kernel(const unsigned short* __restrict__ yo,
                                                 const float* __restrict__ xf,
                                                 const unsigned short* __restrict__ xb,
                                                 const float* __restrict__ gamma, const float* __restrict__ beta,
                                                 float* __restrict__ of, unsigned short* __restrict__ ob,
                                                 int in_f32, int out_f32, int layer) {
    int wave = threadIdx.x >> 6, lane = threadIdx.x & 63;
    size_t row = (size_t)blockIdx.x * 4 + wave;
    const unsigned short* yp = yo + row * H + lane * 8;
    short8 yv = *reinterpret_cast<const short8*>(yp);
    float v[8];
    if (in_f32) {
        const float* xp = xf + row * H + lane * 8;
        float4 x0 = *(const float4*)(xp);
        float4 x1 = *(const float4*)(xp + 4);
        v[0] = bf2f((unsigned short)yv[0]) + x0.x; v[1] = bf2f((unsigned short)yv[1]) + x0.y;
        v[2] = bf2f((unsigned short)yv[2]) + x0.z; v[3] = bf2f((unsigned short)yv[3]) + x0.w;
        v[4] = bf2f((unsigned short)yv[4]) + x1.x; v[5] = bf2f((unsigned short)yv[5]) + x1.y;
        v[6] = bf2f((unsigned short)yv[6]) + x1.z; v[7] = bf2f((unsigned short)yv[7]) + x1.w;
    } else {
        const unsigned short* xp = xb + row * H + lane * 8;
        short8 xv = *reinterpret_cast<const short8*>(xp);
#pragma unroll
        for (int i = 0; i < 8; i++)
            v[i] = bf2f((unsigned short)yv[i]) + bf2f((unsigned short)xv[i]);
    }
    float s = 0.f, s2 = 0.f;
#pragma unroll
    for (int i = 0; i < 8; i++) { s += v[i]; s2 = fmaf(v[i], v[i], s2); }
#pragma unroll
    for (int off = 32; off; off >>= 1) {
        s += __shfl_xor(s, off);
        s2 += __shfl_xor(s2, off);
    }
    float mu = s * (1.0f / H);
    float var = s2 * (1.0f / H) - mu * mu;
    float inv = rsqrtf(var + 1e-5f);
    const float* gl = gamma + layer * H + lane * 8;
    const float* bl = beta + layer * H + lane * 8;
    float o[8];
#pragma unroll
    for (int i = 0; i < 8; i++)
        o[i] = (v[i] - mu) * inv * gl[i] + bl[i];
    if (out_f32) {
        float* op = of + row * H + lane * 8;
        *(float4*)(op) = make_float4(o[0], o[1], o[2], o[3]);
        *(float4*)(op + 4) = make_float4(o[4], o[5], o[6], o[7]);
    } else {
        unsigned short* op = ob + row * H + lane * 8;
        uint2 p0 = pack4bf(o[0], o[1], o[2], o[3]);
        uint2 p1 = pack4bf(o[4], o[5], o[6], o[7]);
        *(uint2*)(op) = p0;
        *(uint2*)(op + 4) = p1;
    }
}

extern "C" void kernel_launch(void* const* d_in, const int* in_sizes, int n_in,
                              void* d_out, int out_size, void* d_ws, size_t ws_size,
                              hipStream_t stream) {
    const float* x          = (const float*)d_in[0];
    const float* log_dt     = (const float*)d_in[1];
    const float* A_imag     = (const float*)d_in[2];
    const float* log_A_real = (const float*)d_in[3];
    const float* C          = (const float*)d_in[4];
    const float* D          = (const float*)d_in[5];
    const float* W          = (const float*)d_in[6];
    const float* bias       = (const float*)d_in[7];
    const float* gamma      = (const float*)d_in[8];
    const float* beta       = (const float*)d_in[9];

    char* ws = (char*)d_ws;
    unsigned short* xR   = (unsigned short*)(ws + 0);           // bf16 residual stream
    unsigned short* Vbuf = (unsigned short*)(ws + 67108864);    // V
    unsigned short* u_t  = (unsigned short*)(ws + 100663296);
    unsigned short* ybf  = (unsigned short*)(ws + 100663296);   // overlay: after ssm, u_t dead
    unsigned short* y_t  = (unsigned short*)(ws + 134217728);
    unsigned short* yo   = (unsigned short*)(ws + 134217728);   // overlay: after gelu_t2, y_t dead
    unsigned short* Wbf  = (unsigned short*)(ws + 167772160);
    unsigned short* Wstb = (unsigned short*)(ws + 171966464);   // Wstate
    unsigned short* kmat = (unsigned short*)(ws + 176160768);
    float*          dA   = (float*)(ws + 176422912);
    float*          Ct   = (float*)(ws + 176947200);
    float* xout_final    = (float*)d_out;

    wconv_kernel<<<NL * 2 * H * H / 256, 256, 0, stream>>>(W, Wbf);
    params_kernel<<<NL * N2 * H / 256, 256, 0, stream>>>(log_dt, A_imag, log_A_real, C, dA, Ct);
    kergen_k_kernel<<<NL * H * 64 / 256, 256, 0, stream>>>(dA, Ct, kmat);

    for (int layer = 0; layer < NL; ++layer) {
        if (layer == 0)
            t1_f32_kernel<<<4096, 256, 0, stream>>>(x, u_t);
        // layers >=1: u_t was already produced (transposed) by ln_t of the previous layer
        kergenWV_kernel<<<H * 64 * 64 / 256, 256, 0, stream>>>(dA, Ct, Wstb, Vbuf, layer);
        ssm_kernel<<<dim3(H, Bsz), 256, 0, stream>>>(u_t, kmat, Wstb, Vbuf, dA, D, y_t, layer);
        gelu_t2_kernel<<<4096, 256, 0, stream>>>(y_t, ybf);
        gemm_glu_kernel<<<dim3(BT / 128, H / 64), 256, 0, stream>>>(ybf, Wbf, bias, yo, layer);
        if (layer < NL - 1) {
            ln_t_kernel<<<BT / 64, 256, 0, stream>>>(yo, x, xR, gamma, beta,
                                                     xR, u_t, (layer == 0) ? 1 : 0, layer);
        } else {
            ln_kernel<<<BT / 4, 256, 0, stream>>>(yo, x, xR, gamma, beta,
                                                  xout_final, xR, 0, 1, layer);
        }
    }
}

// Round 9
// 770.441 us; speedup vs baseline: 1.2405x; 1.0798x over previous
//
#include <hip/hip_runtime.h>
#include <hip/hip_bf16.h>
#include <math.h>

#define H 512
#define NL 4
#define N2 32
#define Bsz 8
#define Lseq 4096
#define BT (Bsz*Lseq)        // 32768 total positions
#define LC2 64               // chunk length
#define NCC (BT/LC2)         // 512 chunks total
#define CPB (Lseq/LC2)       // 64 chunks per batch element

typedef __attribute__((ext_vector_type(8))) short short8;   // 8 bf16
typedef __attribute__((ext_vector_type(4))) float float4v;

// ---------------- ws layout (bytes) ----------------
// 0         : xR   (bf16 BT*H residual)        33554432
// 67108864  : Vbuf (bf16 H*64*64, V)            4194304
// 100663296 : u_t  (bf16 H*BT) / ybf overlay   33554432
// 134217728 : y_t  (bf16 H*BT) / yo overlay    33554432
// 167772160 : Wbf  (bf16 NL*2H*H)               4194304
// 171966464 : Wst  (bf16 H*64*64, Wstate)       4194304
// 176160768 : kmat (bf16 NL*H*64)                262144
// 176422912 : dA   (fp32 NL*N2*2*H)              524288
// 176947200 : Ct   (fp32 NL*N2*2*H)              524288

__device__ __forceinline__ float bf2f(unsigned short u) {
    union { unsigned int i; float f; } x; x.i = ((unsigned int)u) << 16; return x.f;
}
__device__ __forceinline__ unsigned short f2bf(float f) {
    union { float f; unsigned int i; } x; x.f = f;
    unsigned int u = x.i + 0x7fff + ((x.i >> 16) & 1);
    return (unsigned short)(u >> 16);
}
__device__ __forceinline__ uint2 pack4bf(float a, float b, float c, float d) {
    uint2 r;
    r.x = (unsigned)f2bf(a) | ((unsigned)f2bf(b) << 16);
    r.y = (unsigned)f2bf(c) | ((unsigned)f2bf(d) << 16);
    return r;
}
__device__ __forceinline__ void async_copy16(const void* g, void* l) {
    __builtin_amdgcn_global_load_lds(
        (const __attribute__((address_space(1))) void*)g,
        (__attribute__((address_space(3))) void*)l, 16, 0, 0);
}

// ---------- convert W to bf16 ----------
__global__ void wconv_kernel(const float* __restrict__ W, unsigned short* __restrict__ Wbf) {
    int tid = blockIdx.x * 256 + threadIdx.x;
    Wbf[tid] = f2bf(W[tid]);
}

// ---------- per-(layer,n,h): dA = log(lambda), Ct = 2C(lambda-1)/A ----------
__global__ void params_kernel(const float* __restrict__ log_dt, const float* __restrict__ A_imag,
                              const float* __restrict__ log_A_real, const float* __restrict__ Cin,
                              float* __restrict__ dA, float* __restrict__ Ct) {
    int tid = blockIdx.x * 256 + threadIdx.x;   // ((layer*N2+n)*H + h)
    int h = tid % H;
    int n = (tid / H) % N2;
    int layer = tid / (H * N2);
    float dt = expf(log_dt[layer * H + h]);
    int pidx = (layer * H + h) * N2 + n;
    float Are = -expf(log_A_real[pidx]);
    float Aim = A_imag[pidx];
    float dre = Are * dt, dim = Aim * dt;
    float er = expf(dre);
    float lre = er * cosf(dim), lim = er * sinf(dim);
    float nre = lre - 1.0f, nim = lim;
    float inv = 1.0f / (Are * Are + Aim * Aim);
    float tre = (nre * Are + nim * Aim) * inv;
    float tim = (nim * Are - nre * Aim) * inv;
    float Ccre = Cin[pidx * 2], Ccim = Cin[pidx * 2 + 1];
    int oidx = ((layer * N2 + n) * 2) * H + h;
    dA[oidx] = dre;  dA[oidx + H] = dim;
    Ct[oidx] = 2.0f * (Ccre * tre - Ccim * tim);
    Ct[oidx + H] = 2.0f * (Ccre * tim + Ccim * tre);
}

// ---------- kernels k[d] = Re sum_n Ct_n lambda_n^d, all layers ----------
__global__ void kergen_k_kernel(const float* __restrict__ dA, const float* __restrict__ Ct,
                                unsigned short* __restrict__ kmat) {
    int t = blockIdx.x * 256 + threadIdx.x;     // (layer*H + h)*64 + d
    int d = t & 63;
    int h = (t >> 6) & (H - 1);
    int layer = t >> 15;
    float fd = (float)d;
    float sum = 0.f;
    for (int n = 0; n < N2; n++) {
        int base = ((layer * N2 + n) * 2) * H + h;
        float dre = dA[base], dim = dA[base + H];
        float Ctr = Ct[base], Cti = Ct[base + H];
        float e = expf(dre * fd);
        sum += Ctr * e * cosf(dim * fd) - Cti * e * sinf(dim * fd);
    }
    kmat[t] = f2bf(sum);
}

// ---------- merged Wstate + V generation (same grid decomposition) ----------
__global__ void kergenWV_kernel(const float* __restrict__ dA, const float* __restrict__ Ct,
                                unsigned short* __restrict__ Wst, unsigned short* __restrict__ Vl,
                                int layer) {
    int t = blockIdx.x * 256 + threadIdx.x;
    int h = t >> 12;
    {   // Wstate element
        int j = t & 63;
        int r = (t >> 6) & 63;
        int n = r >> 1;
        int base = ((layer * N2 + n) * 2) * H + h;
        float dre = dA[base], dim = dA[base + H];
        float p = (float)(63 - j);
        float e = expf(dre * p);
        Wst[t] = f2bf((r & 1) ? e * sinf(dim * p) : e * cosf(dim * p));
    }
    {   // V element
        int c2 = t & 63;
        int l = (t >> 6) & 63;
        int n = c2 >> 1;
        int base = ((layer * N2 + n) * 2) * H + h;
        float dre = dA[base], dim = dA[base + H];
        float Ctr = Ct[base], Cti = Ct[base + H];
        float q = (float)(l + 1);
        float e = expf(dre * q);
        float ar = e * cosf(dim * q), ai = e * sinf(dim * q);
        float vre = Ctr * ar - Cti * ai;
        float vim = Ctr * ai + Cti * ar;
        Vl[t] = f2bf((c2 & 1) ? -vim : vre);
    }
}

// ---------- transpose x fp32 (BT,H) -> u_t bf16 (H,BT)  [layer 0 only] ----------
__global__ __launch_bounds__(256) void t1_f32_kernel(const float* __restrict__ xi,
                                                     unsigned short* __restrict__ ut) {
    __shared__ float tile[64][68];
    int bx = blockIdx.x;
    int pt = bx & 511, ht = bx >> 9;
    int p0 = pt * 64, h0 = ht * 64;
    int t = threadIdx.x;
    int jr = t & 15, ib = t >> 4;
#pragma unroll
    for (int pass = 0; pass < 4; pass++) {
        int i = ib + pass * 16;
        float4 v = *(const float4*)(xi + (size_t)(p0 + i) * H + h0 + jr * 4);
        *(float4*)(&tile[i][jr * 4]) = v;   // 272B row stride -> 16B aligned
    }
    __syncthreads();
#pragma unroll
    for (int pass = 0; pass < 4; pass++) {
        int i2 = ib + pass * 16;
        int j2 = jr * 4;
        uint2 pk = pack4bf(tile[j2][i2], tile[j2 + 1][i2], tile[j2 + 2][i2], tile[j2 + 3][i2]);
        *(uint2*)(ut + (size_t)(h0 + i2) * BT + p0 + j2) = pk;
    }
}

// ---------- FUSED SSM v4: 2 batches per block (ILP-2 scan, shared fragments) ----------
// Grid (H, Bsz/2). Toeplitz, Wst/V/T fragments, and the lambda^k power chain are
// computed once per block and reused across both batch elements; the two scans run
// as interleaved independent dependency chains.
__global__ __launch_bounds__(256) void ssm_kernel(const unsigned short* __restrict__ ut,
                                                  const unsigned short* __restrict__ kmat,
                                                  const unsigned short* __restrict__ Wst,
                                                  const unsigned short* __restrict__ Vl,
                                                  const float* __restrict__ dA,
                                                  const float* __restrict__ Dp,
                                                  unsigned short* __restrict__ yt, int layer) {
    __shared__ unsigned short T[64][72];       // Toeplitz (shared across both b)
    __shared__ unsigned short Sl[2][64][72];   // per-b local -> entering states
    __shared__ float Tw[2][4][64];             // per-b fp32 wave segment totals
    int h = blockIdx.x, b0 = blockIdx.y * 2;
    int t = threadIdx.x;
    const unsigned short* km = kmat + ((size_t)layer * H + h) * 64;
    {   // build lower-triangular Toeplitz T[l][j] = k[l-j]
        int l = t >> 2, j0 = (t & 3) * 16;
#pragma unroll
        for (int g = 0; g < 2; g++) {
            short8 v;
#pragma unroll
            for (int e = 0; e < 8; e++) {
                int j = j0 + g * 8 + e;
                v[e] = (j <= l) ? (short)km[l - j] : (short)0;
            }
            *reinterpret_cast<short8*>(&T[l][j0 + g * 8]) = v;
        }
    }
    int wave = t >> 6, lane = t & 63;
    int r16 = lane & 15, quad = lane >> 4;
    const unsigned short* uh0 = ut + (size_t)h * BT + (size_t)b0 * Lseq;
    const unsigned short* uh1 = uh0 + Lseq;
    const unsigned short* wh = Wst + (size_t)h * 64 * 64;
    const unsigned short* vh = Vl + (size_t)h * 64 * 64;

    // ---- phase 1: local states for both b; A-fragments (Wst) loaded once ----
    {
        int cc0 = wave * 16;
        float4v acc[2][4] = {};
#pragma unroll
        for (int k0 = 0; k0 < 64; k0 += 32) {
            short8 af[4];
#pragma unroll
            for (int mt = 0; mt < 4; mt++)
                af[mt] = *reinterpret_cast<const short8*>(wh + (mt * 16 + r16) * 64 + k0 + quad * 8);
            short8 bf0 = *reinterpret_cast<const short8*>(uh0 + (size_t)(cc0 + r16) * 64 + k0 + quad * 8);
            short8 bf1 = *reinterpret_cast<const short8*>(uh1 + (size_t)(cc0 + r16) * 64 + k0 + quad * 8);
#pragma unroll
            for (int mt = 0; mt < 4; mt++) {
                acc[0][mt] = __builtin_amdgcn_mfma_f32_16x16x32_bf16(af[mt], bf0, acc[0][mt], 0, 0, 0);
                acc[1][mt] = __builtin_amdgcn_mfma_f32_16x16x32_bf16(af[mt], bf1, acc[1][mt], 0, 0, 0);
            }
        }
        int cc = cc0 + r16;
#pragma unroll
        for (int i = 0; i < 2; i++)
#pragma unroll
            for (int mt = 0; mt < 4; mt++) {
                uint2 pk = pack4bf(acc[i][mt][0], acc[i][mt][1], acc[i][mt][2], acc[i][mt][3]);
                *(uint2*)(&Sl[i][cc][mt * 16 + quad * 4]) = pk;
            }
    }
    __syncthreads();

    // ---- phase 2: segmented scan, two independent chains interleaved ----
    {
        int r = lane;
        int n = r >> 1;
        int base = ((layer * N2 + n) * 2) * H + h;
        float dre = dA[base], dim = dA[base + H];
        float e1 = expf(dre * 64.f);
        float Lr = e1 * cosf(dim * 64.f), Li = e1 * sinf(dim * 64.f);
        float Ls = (r & 1) ? Li : -Li;            // constant-split complex mult helper
        int c0 = wave * 16;

        float eloc0[16], eloc1[16];
        float s0 = 0.f, s1 = 0.f;
#pragma unroll
        for (int k = 0; k < 16; k++) {
            float p0 = bf2f(Sl[0][c0 + k][r]);
            float p1 = bf2f(Sl[1][c0 + k][r]);
            eloc0[k] = s0; eloc1[k] = s1;
            float sp0 = __shfl_xor(s0, 1);
            float sp1 = __shfl_xor(s1, 1);
            s0 = fmaf(Lr, s0, fmaf(Ls, sp0, p0));
            s1 = fmaf(Lr, s1, fmaf(Ls, sp1, p1));
        }
        Tw[0][wave][r] = s0;
        Tw[1][wave][r] = s1;
        __syncthreads();

        // carry: C_w = sum_{j<w} L16^{w-1-j} T_j,  L16 = Lc^16 = lambda^1024
        float e16 = expf(dre * 1024.f);
        float Lr16 = e16 * cosf(dim * 1024.f), Li16 = e16 * sinf(dim * 1024.f);
        float Ls16 = (r & 1) ? Li16 : -Li16;
        float C0 = 0.f, C1 = 0.f;
        for (int j = 0; j < wave; j++) {          // wave-uniform branch
            float Tj0 = Tw[0][j][r], Tj1 = Tw[1][j][r];
            float Cp0 = __shfl_xor(C0, 1);
            float Cp1 = __shfl_xor(C1, 1);
            C0 = fmaf(Lr16, C0, fmaf(Ls16, Cp0, Tj0));
            C1 = fmaf(Lr16, C1, fmaf(Ls16, Cp1, Tj1));
        }
        float cpp0 = __shfl_xor(C0, 1);
        float cpp1 = __shfl_xor(C1, 1);

        // apply: E[c0+k] = eloc[k] + (Lc^k (x) C); pw chain shared across both b
        float pw = (r & 1) ? 0.f : 1.f;           // Lc^0 = 1 + 0i (lane-split)
#pragma unroll
        for (int k = 0; k < 16; k++) {
            float pp = __shfl_xor(pw, 1);
            float u1 = (r & 1) ? pp : pw;
            float u2 = (r & 1) ? pw : pp;
            float tt0 = u2 * cpp0, tt1 = u2 * cpp1;
            float ead0 = fmaf(u1, C0, (r & 1) ? tt0 : -tt0);
            float ead1 = fmaf(u1, C1, (r & 1) ? tt1 : -tt1);
            Sl[0][c0 + k][r] = f2bf(eloc0[k] + ead0);
            Sl[1][c0 + k][r] = f2bf(eloc1[k] + ead1);
            pw = fmaf(Lr, pw, Ls * pp);           // pw <- Lc (x) pw
        }
    }
    __syncthreads();

    // ---- phase 3: y = T*u + V*E + D*u for both b; A-fragments loaded once ----
    {
        int cc0 = wave * 16;
        float4v acc[2][4] = {};
#pragma unroll
        for (int k0 = 0; k0 < 64; k0 += 32) {    // Toeplitz part
            short8 af[4];
#pragma unroll
            for (int mt = 0; mt < 4; mt++)
                af[mt] = *reinterpret_cast<const short8*>(&T[mt * 16 + r16][k0 + quad * 8]);
            short8 bf0 = *reinterpret_cast<const short8*>(uh0 + (size_t)(cc0 + r16) * 64 + k0 + quad * 8);
            short8 bf1 = *reinterpret_cast<const short8*>(uh1 + (size_t)(cc0 + r16) * 64 + k0 + quad * 8);
#pragma unroll
            for (int mt = 0; mt < 4; mt++) {
                acc[0][mt] = __builtin_amdgcn_mfma_f32_16x16x32_bf16(af[mt], bf0, acc[0][mt], 0, 0, 0);
                acc[1][mt] = __builtin_amdgcn_mfma_f32_16x16x32_bf16(af[mt], bf1, acc[1][mt], 0, 0, 0);
            }
        }
#pragma unroll
        for (int k0 = 0; k0 < 64; k0 += 32) {    // entering-state correction
            short8 af[4];
#pragma unroll
            for (int mt = 0; mt < 4; mt++)
                af[mt] = *reinterpret_cast<const short8*>(vh + (mt * 16 + r16) * 64 + k0 + quad * 8);
            short8 bf0 = *reinterpret_cast<const short8*>(&Sl[0][cc0 + r16][k0 + quad * 8]);
            short8 bf1 = *reinterpret_cast<const short8*>(&Sl[1][cc0 + r16][k0 + quad * 8]);
#pragma unroll
            for (int mt = 0; mt < 4; mt++) {
                acc[0][mt] = __builtin_amdgcn_mfma_f32_16x16x32_bf16(af[mt], bf0, acc[0][mt], 0, 0, 0);
                acc[1][mt] = __builtin_amdgcn_mfma_f32_16x16x32_bf16(af[mt], bf1, acc[1][mt], 0, 0, 0);
            }
        }
        float Dh = Dp[layer * H + h];
        int cc = cc0 + r16;
#pragma unroll
        for (int i = 0; i < 2; i++) {
            const unsigned short* uhi = (i == 0) ? uh0 : uh1;
            unsigned short* yh = yt + (size_t)h * BT + (size_t)(b0 + i) * Lseq;
#pragma unroll
            for (int mt = 0; mt < 4; mt++) {
                size_t p = (size_t)cc * 64 + mt * 16 + quad * 4;
                ushort4 uu = *(const ushort4*)(uhi + p);
                float o0 = acc[i][mt][0] + Dh * bf2f(uu.x);
                float o1 = acc[i][mt][1] + Dh * bf2f(uu.y);
                float o2 = acc[i][mt][2] + Dh * bf2f(uu.z);
                float o3 = acc[i][mt][3] + Dh * bf2f(uu.w);
                *(uint2*)(yh + p) = pack4bf(o0, o1, o2, o3);
            }
        }
    }
}

// ---------- fused GELU + transpose: y_t (H,BT pre-gelu) -> ybf (BT,H gelu'd) ----------
__global__ __launch_bounds__(256) void gelu_t2_kernel(const unsigned short* __restrict__ yt,
                                                      unsigned short* __restrict__ yb) {
    __shared__ unsigned short tile[64][72];
    int bx = blockIdx.x;
    int pt = bx & 511, ht = bx >> 9;
    int p0 = pt * 64, h0 = ht * 64;
    int t = threadIdx.x;
    int jr = t & 7, ib = t >> 3;
#pragma unroll
    for (int pass = 0; pass < 2; pass++) {
        int i = ib + pass * 32;
        short8 v = *reinterpret_cast<const short8*>(yt + (size_t)(h0 + i) * BT + p0 + jr * 8);
        short8 w;
#pragma unroll
        for (int e = 0; e < 8; e++) {
            float y = bf2f((unsigned short)v[e]);
            float g = 0.5f * y * (1.0f + erff(y * 0.70710678118654752f));
            w[e] = (short)f2bf(g);
        }
        *reinterpret_cast<short8*>(&tile[i][jr * 8]) = w;
    }
    __syncthreads();
    int pp = t >> 2, hg = t & 3;
    short8 o0, o1;
#pragma unroll
    for (int r = 0; r < 8; r++) o0[r] = (short)tile[hg * 16 + r][pp];
#pragma unroll
    for (int r = 0; r < 8; r++) o1[r] = (short)tile[hg * 16 + 8 + r][pp];
    unsigned short* dst = yb + (size_t)(p0 + pp) * H + h0 + hg * 16;
    *reinterpret_cast<short8*>(dst) = o0;
    *reinterpret_cast<short8*>(dst + 8) = o1;
}

// ---------- fused 1x1 conv (LDS-tiled, bank-conflict-free swizzle) + bias + GLU ----------
// v2 (proven): triple-buffered LDS, depth-2 prefetch, raw s_barrier + counted vmcnt.
__global__ __launch_bounds__(256) void gemm_glu_kernel(const unsigned short* __restrict__ ybf,
                                                       const unsigned short* __restrict__ Wbf,
                                                       const float* __restrict__ bias,
                                                       unsigned short* __restrict__ yo, int layer) {
    __shared__ unsigned short As[3][128 * 32];
    __shared__ unsigned short Bs[3][128 * 32];
    int tid = threadIdx.x;
    int wave = tid >> 6, lane = tid & 63;
    int wr = wave >> 1, wc = wave & 1;
    int r16 = lane & 15, quad = lane >> 4;
    int m0 = blockIdx.x * 128;
    int o0 = blockIdx.y * 64;
    const unsigned short* Wl = Wbf + (size_t)layer * 2 * H * H;

    int srow = lane >> 2;
    int scol = ((lane & 3) ^ ((srow >> 1) & 3)) * 8;
    const unsigned short* aS0 = ybf + ((size_t)(m0 + wave * 16 + srow)) * H + scol;
    const unsigned short* aS1 = aS0 + (size_t)64 * H;
    const unsigned short* bSA = Wl + ((size_t)(o0 + wave * 16 + srow)) * H + scol;
    const unsigned short* bSG = bSA + (size_t)512 * H;
    const int aoff0 = (wave * 16) * 32;
    const int aoff1 = (64 + wave * 16) * 32;

    int rcol = (quad ^ ((r16 >> 1) & 3)) * 8;

    float4v acc_a[4][2] = {}, acc_g[4][2] = {};

    async_copy16(aS0,      &As[0][aoff0]);
    async_copy16(aS1,      &As[0][aoff1]);
    async_copy16(bSA,      &Bs[0][aoff0]);
    async_copy16(bSG,      &Bs[0][aoff1]);
    async_copy16(aS0 + 32, &As[1][aoff0]);
    async_copy16(aS1 + 32, &As[1][aoff1]);
    async_copy16(bSA + 32, &Bs[1][aoff0]);
    async_copy16(bSG + 32, &Bs[1][aoff1]);
    asm volatile("s_waitcnt vmcnt(4)" ::: "memory");
    __builtin_amdgcn_s_barrier();

#pragma unroll
    for (int ks = 0; ks < 16; ++ks) {
        const int b = ks % 3;
        if (ks < 14) {
            const int nb = (ks + 2) % 3;
            const int kn = (ks + 2) * 32;
            async_copy16(aS0 + kn, &As[nb][aoff0]);
            async_copy16(aS1 + kn, &As[nb][aoff1]);
            async_copy16(bSA + kn, &Bs[nb][aoff0]);
            async_copy16(bSG + kn, &Bs[nb][aoff1]);
        }

        short8 af[4], ba[2], bg[2];
#pragma unroll
        for (int mi = 0; mi < 4; mi++)
            af[mi] = *reinterpret_cast<const short8*>(&As[b][(wr * 64 + mi * 16 + r16) * 32 + rcol]);
#pragma unroll
        for (int ni = 0; ni < 2; ni++) {
            ba[ni] = *reinterpret_cast<const short8*>(&Bs[b][(wc * 32 + ni * 16 + r16) * 32 + rcol]);
            bg[ni] = *reinterpret_cast<const short8*>(&Bs[b][(64 + wc * 32 + ni * 16 + r16) * 32 + rcol]);
        }
#pragma unroll
        for (int mi = 0; mi < 4; mi++)
#pragma unroll
            for (int ni = 0; ni < 2; ni++) {
                acc_a[mi][ni] = __builtin_amdgcn_mfma_f32_16x16x32_bf16(af[mi], ba[ni], acc_a[mi][ni], 0, 0, 0);
                acc_g[mi][ni] = __builtin_amdgcn_mfma_f32_16x16x32_bf16(af[mi], bg[ni], acc_g[mi][ni], 0, 0, 0);
            }

        if (ks < 14) {
            asm volatile("s_waitcnt vmcnt(4) lgkmcnt(0)" ::: "memory");
            __builtin_amdgcn_s_barrier();
        } else if (ks == 14) {
            asm volatile("s_waitcnt vmcnt(0) lgkmcnt(0)" ::: "memory");
            __builtin_amdgcn_s_barrier();
        }
    }

    const float* bl = bias + layer * 2 * H;
#pragma unroll
    for (int ni = 0; ni < 2; ni++) {
        int o = o0 + wc * 32 + ni * 16 + r16;
        float ba_ = bl[o], bg_ = bl[H + o];
#pragma unroll
        for (int mi = 0; mi < 4; mi++)
#pragma unroll
            for (int r = 0; r < 4; r++) {
                int l = m0 + wr * 64 + mi * 16 + quad * 4 + r;
                float av = acc_a[mi][ni][r] + ba_;
                float gv = acc_g[mi][ni][r] + bg_;
                yo[(size_t)l * H + o] = f2bf(av * (1.0f / (1.0f + expf(-gv))));
            }
    }
}

// ---------- fused residual + LayerNorm + transpose-out (layers 0..2) ----------
__global__ __launch_bounds__(256) void ln_t_kernel(const unsigned short* __restrict__ yo,
                                                   const float* __restrict__ xf,
                                                   const unsigned short* __restrict__ xb,
                                                   const float* __restrict__ gamma,
                                                   const float* __restrict__ beta,
                                                   unsigned short* __restrict__ xR,
                                                   unsigned short* __restrict__ ut,
                                                   int in_f32, int layer) {
    __shared__ unsigned short tl[64][520];
    int t = threadIdx.x;
    int p0 = blockIdx.x * 64;
    int lane8 = t & 7;
    int rowb = t >> 3;
    const float* gl = gamma + layer * H;
    const float* bl = beta + layer * H;
#pragma unroll
    for (int rr = 0; rr < 2; rr++) {
        int row = rowb + rr * 32;
        size_t gbase = (size_t)(p0 + row) * H;
        float v[64];
        float s = 0.f, s2 = 0.f;
#pragma unroll
        for (int cc = 0; cc < 8; cc++) {
            int h0 = (lane8 + cc * 8) * 8;
            short8 yv = *reinterpret_cast<const short8*>(yo + gbase + h0);
            if (in_f32) {
                float4 x0 = *(const float4*)(xf + gbase + h0);
                float4 x1 = *(const float4*)(xf + gbase + h0 + 4);
                v[cc * 8 + 0] = bf2f((unsigned short)yv[0]) + x0.x;
                v[cc * 8 + 1] = bf2f((unsigned short)yv[1]) + x0.y;
                v[cc * 8 + 2] = bf2f((unsigned short)yv[2]) + x0.z;
                v[cc * 8 + 3] = bf2f((unsigned short)yv[3]) + x0.w;
                v[cc * 8 + 4] = bf2f((unsigned short)yv[4]) + x1.x;
                v[cc * 8 + 5] = bf2f((unsigned short)yv[5]) + x1.y;
                v[cc * 8 + 6] = bf2f((unsigned short)yv[6]) + x1.z;
                v[cc * 8 + 7] = bf2f((unsigned short)yv[7]) + x1.w;
            } else {
                short8 xv = *reinterpret_cast<const short8*>(xb + gbase + h0);
#pragma unroll
                for (int i = 0; i < 8; i++)
                    v[cc * 8 + i] = bf2f((unsigned short)yv[i]) + bf2f((unsigned short)xv[i]);
            }
#pragma unroll
            for (int i = 0; i < 8; i++) { s += v[cc * 8 + i]; s2 = fmaf(v[cc * 8 + i], v[cc * 8 + i], s2); }
        }
        s += __shfl_xor(s, 1);  s2 += __shfl_xor(s2, 1);
        s += __shfl_xor(s, 2);  s2 += __shfl_xor(s2, 2);
        s += __shfl_xor(s, 4);  s2 += __shfl_xor(s2, 4);
        float mu = s * (1.0f / H);
        float var = s2 * (1.0f / H) - mu * mu;
        float inv = rsqrtf(var + 1e-5f);
#pragma unroll
        for (int cc = 0; cc < 8; cc++) {
            int h0 = (lane8 + cc * 8) * 8;
            float4 g0 = *(const float4*)(gl + h0);
            float4 g1 = *(const float4*)(gl + h0 + 4);
            float4 b0 = *(const float4*)(bl + h0);
            float4 b1 = *(const float4*)(bl + h0 + 4);
            short8 pk;
            pk[0] = (short)f2bf((v[cc * 8 + 0] - mu) * inv * g0.x + b0.x);
            pk[1] = (short)f2bf((v[cc * 8 + 1] - mu) * inv * g0.y + b0.y);
            pk[2] = (short)f2bf((v[cc * 8 + 2] - mu) * inv * g0.z + b0.z);
            pk[3] = (short)f2bf((v[cc * 8 + 3] - mu) * inv * g0.w + b0.w);
            pk[4] = (short)f2bf((v[cc * 8 + 4] - mu) * inv * g1.x + b1.x);
            pk[5] = (short)f2bf((v[cc * 8 + 5] - mu) * inv * g1.y + b1.y);
            pk[6] = (short)f2bf((v[cc * 8 + 6] - mu) * inv * g1.z + b1.z);
            pk[7] = (short)f2bf((v[cc * 8 + 7] - mu) * inv * g1.w + b1.w);
            *reinterpret_cast<short8*>(xR + gbase + h0) = pk;
            *reinterpret_cast<short8*>(&tl[row][h0]) = pk;
        }
    }
    __syncthreads();
#pragma unroll
    for (int hh = 0; hh < 2; hh++) {
        int h = t + hh * 256;
        unsigned short* dst = ut + (size_t)h * BT + p0;
#pragma unroll
        for (int pc = 0; pc < 8; pc++) {
            short8 o;
#pragma unroll
            for (int e = 0; e < 8; e++) o[e] = (short)tl[pc * 8 + e][h];
            *reinterpret_cast<short8*>(dst + pc * 8) = o;
        }
    }
}

// ---------- residual + LayerNorm (final layer: fp32 out) ----------
__global__ __launch_bounds__(256) void ln_kernel(const unsigned short* __restrict__ yo,
                                                 const float* __restrict__ xf,
                                                 const unsigned short* __restrict__ xb,
                                                 const float* __restrict__ gamma, const float* __restrict__ beta,
                                                 float* __restrict__ of, unsigned short* __restrict__ ob,
                                                 int in_f32, int out_f32, int layer) {
    int wave = threadIdx.x >> 6, lane = threadIdx.x & 63;
    size_t row = (size_t)blockIdx.x * 4 + wave;
    const unsigned short* yp = yo + row * H + lane * 8;
    short8 yv = *reinterpret_cast<const short8*>(yp);
    float v[8];
    if (in_f32) {
        const float* xp = xf + row * H + lane * 8;
        float4 x0 = *(const float4*)(xp);
        float4 x1 = *(const float4*)(xp + 4);
        v[0] = bf2f((unsigned short)yv[0]) + x0.x; v[1] = bf2f((unsigned short)yv[1]) + x0.y;
        v[2] = bf2f((unsigned short)yv[2]) + x0.z; v[3] = bf2f((unsigned short)yv[3]) + x0.w;
        v[4] = bf2f((unsigned short)yv[4]) + x1.x; v[5] = bf2f((unsigned short)yv[5]) + x1.y;
        v[6] = bf2f((unsigned short)yv[6]) + x1.z; v[7] = bf2f((unsigned short)yv[7]) + x1.w;
    } else {
        const unsigned short* xp = xb + row * H + lane * 8;
        short8 xv = *reinterpret_cast<const short8*>(xp);
#pragma unroll
        for (int i = 0; i < 8; i++)
            v[i] = bf2f((unsigned short)yv[i]) + bf2f((unsigned short)xv[i]);
    }
    float s = 0.f, s2 = 0.f;
#pragma unroll
    for (int i = 0; i < 8; i++) { s += v[i]; s2 = fmaf(v[i], v[i], s2); }
#pragma unroll
    for (int off = 32; off; off >>= 1) {
        s += __shfl_xor(s, off);
        s2 += __shfl_xor(s2, off);
    }
    float mu = s * (1.0f / H);
    float var = s2 * (1.0f / H) - mu * mu;
    float inv = rsqrtf(var + 1e-5f);
    const float* gl = gamma + layer * H + lane * 8;
    const float* bl = beta + layer * H + lane * 8;
    float o[8];
#pragma unroll
    for (int i = 0; i < 8; i++)
        o[i] = (v[i] - mu) * inv * gl[i] + bl[i];
    if (out_f32) {
        float* op = of + row * H + lane * 8;
        *(float4*)(op) = make_float4(o[0], o[1], o[2], o[3]);
        *(float4*)(op + 4) = make_float4(o[4], o[5], o[6], o[7]);
    } else {
        unsigned short* op = ob + row * H + lane * 8;
        uint2 p0 = pack4bf(o[0], o[1], o[2], o[3]);
        uint2 p1 = pack4bf(o[4], o[5], o[6], o[7]);
        *(uint2*)(op) = p0;
        *(uint2*)(op + 4) = p1;
    }
}

extern "C" void kernel_launch(void* const* d_in, const int* in_sizes, int n_in,
                              void* d_out, int out_size, void* d_ws, size_t ws_size,
                              hipStream_t stream) {
    const float* x          = (const float*)d_in[0];
    const float* log_dt     = (const float*)d_in[1];
    const float* A_imag     = (const float*)d_in[2];
    const float* log_A_real = (const float*)d_in[3];
    const float* C          = (const float*)d_in[4];
    const float* D          = (const float*)d_in[5];
    const float* W          = (const float*)d_in[6];
    const float* bias       = (const float*)d_in[7];
    const float* gamma      = (const float*)d_in[8];
    const float* beta       = (const float*)d_in[9];

    char* ws = (char*)d_ws;
    unsigned short* xR   = (unsigned short*)(ws + 0);           // bf16 residual stream
    unsigned short* Vbuf = (unsigned short*)(ws + 67108864);    // V
    unsigned short* u_t  = (unsigned short*)(ws + 100663296);
    unsigned short* ybf  = (unsigned short*)(ws + 100663296);   // overlay: after ssm, u_t dead
    unsigned short* y_t  = (unsigned short*)(ws + 134217728);
    unsigned short* yo   = (unsigned short*)(ws + 134217728);   // overlay: after gelu_t2, y_t dead
    unsigned short* Wbf  = (unsigned short*)(ws + 167772160);
    unsigned short* Wstb = (unsigned short*)(ws + 171966464);   // Wstate
    unsigned short* kmat = (unsigned short*)(ws + 176160768);
    float*          dA   = (float*)(ws + 176422912);
    float*          Ct   = (float*)(ws + 176947200);
    float* xout_final    = (float*)d_out;

    wconv_kernel<<<NL * 2 * H * H / 256, 256, 0, stream>>>(W, Wbf);
    params_kernel<<<NL * N2 * H / 256, 256, 0, stream>>>(log_dt, A_imag, log_A_real, C, dA, Ct);
    kergen_k_kernel<<<NL * H * 64 / 256, 256, 0, stream>>>(dA, Ct, kmat);

    for (int layer = 0; layer < NL; ++layer) {
        if (layer == 0)
            t1_f32_kernel<<<4096, 256, 0, stream>>>(x, u_t);
        // layers >=1: u_t was already produced (transposed) by ln_t of the previous layer
        kergenWV_kernel<<<H * 64 * 64 / 256, 256, 0, stream>>>(dA, Ct, Wstb, Vbuf, layer);
        ssm_kernel<<<dim3(H, Bsz / 2), 256, 0, stream>>>(u_t, kmat, Wstb, Vbuf, dA, D, y_t, layer);
        gelu_t2_kernel<<<4096, 256, 0, stream>>>(y_t, ybf);
        gemm_glu_kernel<<<dim3(BT / 128, H / 64), 256, 0, stream>>>(ybf, Wbf, bias, yo, layer);
        if (layer < NL - 1) {
            ln_t_kernel<<<BT / 64, 256, 0, stream>>>(yo, x, xR, gamma, beta,
                                                     xR, u_t, (layer == 0) ? 1 : 0, layer);
        } else {
            ln_kernel<<<BT / 4, 256, 0, stream>>>(yo, x, xR, gamma, beta,
                                                  xout_final, xR, 0, 1, layer);
        }
    }
}